// Round 11
// baseline (220.010 us; speedup 1.0000x reference)
//
#include <hip/hip_runtime.h>
#include <hip/hip_bf16.h>

// Problem constants
#define Bq 32
#define Lq 256
#define Hq 8
#define Eq 16
#define Nn (Bq*Hq)        // 256 sequences
#define T 254             // Lq - 3 + 1
#define A 145             // E + 1 + 128 augmented channels
#define SIG_CH (A + A*A)  // 21170
#define KP 21184          // padded K (mult of 32), bf16 arrays
#define OUT 256
#define TPAD 256          // aug_t row stride (t dimension)
#define OTS 35            // outtile LDS row stride (floats)

typedef __attribute__((ext_vector_type(8))) short short8;
typedef __attribute__((ext_vector_type(8))) unsigned short ushort8;
typedef __attribute__((ext_vector_type(4))) float floatx4;

static __device__ __forceinline__ unsigned short f2bf(float v) {
    unsigned int u = __float_as_uint(v);
    unsigned int r = (u + 0x7FFFu + ((u >> 16) & 1u)) >> 16;
    return (unsigned short)r;
}
static __device__ __forceinline__ float bf2f(unsigned short b) {
    return __uint_as_float(((unsigned int)b) << 16);
}

// ---------------------------------------------------------------------------
// Kernel A: conv1(k=3,16->64) -> conv2(k=1,64->128)+ReLU -> aug_t[n][ch][t].
// grid (4, 256), 256 threads. R10 conv improvements kept:
//   conv1: b128 x reads + b128 w reads (dt-loop unroll 1 caps VGPR)
//   conv2: 4-consecutive-t mapping -> b128 a1s reads; w2 from global.
//   Output staged in LDS outtile, coalesced t-contiguous flush.
// ---------------------------------------------------------------------------
__global__ __launch_bounds__(256) void aug_kernel(
    const float* __restrict__ q,
    const float* __restrict__ w1, const float* __restrict__ b1,
    const float* __restrict__ w2, const float* __restrict__ b2,
    float* __restrict__ aug_t)
{
    __shared__ __align__(16) float w1s[48*64];    // 12KB
    __shared__ __align__(16) float b1s[64];
    __shared__ __align__(16) float b2s[128];
    __shared__ __align__(16) float xs[68*16];     // 4.35KB
    __shared__ __align__(16) float a1s[32*64];    // 8KB
    __shared__ __align__(16) float outs[A*OTS];   // 20.3KB

    const int tid = threadIdx.x;
    const int n = blockIdx.y;
    const int b = n >> 3, h = n & 7;
    const int tb0 = blockIdx.x * 64;

    for (int i = tid; i < 48*64; i += 256) w1s[i] = w1[i];
    if (tid < 64)  b1s[tid] = b1[tid];
    if (tid < 128) b2s[tid] = b2[tid];
    {
        const float4* q4 = (const float4*)q + ((long)(b*Lq)*Hq + h)*4;
        float4* xs4 = (float4*)xs;
        for (int i = tid; i < 68*4; i += 256) {
            int rr = i >> 2, e4 = i & 3;
            int t = tb0 + rr; if (t > 255) t = 255;
            xs4[rr*4 + e4] = q4[t*32 + e4];
        }
    }
    __syncthreads();

    const float inv253 = 1.0f / 253.0f;
    const float4* w2g = (const float4*)w2;   // [i][c/4]

    #pragma unroll
    for (int sub = 0; sub < 2; ++sub) {
        const int t0 = tb0 + sub*32;
        const int l0 = sub*32;

        // ---- conv1: thread = (c-quad, t rows tg & tg+16)
        {
            const int c = (tid & 15) * 4;
            const int tg = tid >> 4;
            float4 bb = *(const float4*)&b1s[c];
            float4 acc0 = bb, acc1 = bb;
            #pragma unroll 1
            for (int dt = 0; dt < 3; ++dt) {
                const float* xra = &xs[(l0 + tg + dt)*16];
                const float* xrb = &xs[(l0 + tg + 16 + dt)*16];
                #pragma unroll
                for (int i4 = 0; i4 < 4; ++i4) {
                    float4 xa = *(const float4*)(xra + i4*4);
                    float4 xb = *(const float4*)(xrb + i4*4);
                    const float* wb = &w1s[(dt*16 + i4*4)*64 + c];
                    float4 w0 = *(const float4*)(wb);
                    float4 wv1 = *(const float4*)(wb + 64);
                    float4 wv2 = *(const float4*)(wb + 128);
                    float4 w3 = *(const float4*)(wb + 192);
                    acc0.x += xa.x*w0.x + xa.y*wv1.x + xa.z*wv2.x + xa.w*w3.x;
                    acc0.y += xa.x*w0.y + xa.y*wv1.y + xa.z*wv2.y + xa.w*w3.y;
                    acc0.z += xa.x*w0.z + xa.y*wv1.z + xa.z*wv2.z + xa.w*w3.z;
                    acc0.w += xa.x*w0.w + xa.y*wv1.w + xa.z*wv2.w + xa.w*w3.w;
                    acc1.x += xb.x*w0.x + xb.y*wv1.x + xb.z*wv2.x + xb.w*w3.x;
                    acc1.y += xb.x*w0.y + xb.y*wv1.y + xb.z*wv2.y + xb.w*w3.y;
                    acc1.z += xb.x*w0.z + xb.y*wv1.z + xb.z*wv2.z + xb.w*w3.z;
                    acc1.w += xb.x*w0.w + xb.y*wv1.w + xb.z*wv2.w + xb.w*w3.w;
                }
            }
            *(float4*)&a1s[(tid >> 4)*64 + c]        = acc0;
            *(float4*)&a1s[((tid >> 4) + 16)*64 + c] = acc1;
        }
        __syncthreads();

        // ---- conv2 + ReLU -> LDS outtile (b128 a1s reads, broadcast)
        {
            const int cqi = tid & 31;
            const int tq  = tid >> 5;
            float4 bb = *(const float4*)&b2s[cqi*4];
            float4 acc[4] = {bb, bb, bb, bb};
            #pragma unroll 2
            for (int i4 = 0; i4 < 16; ++i4) {
                float4 at[4];
                #pragma unroll
                for (int tl = 0; tl < 4; ++tl)
                    at[tl] = *(const float4*)&a1s[(tq*4 + tl)*64 + i4*4];
                #pragma unroll
                for (int k = 0; k < 4; ++k) {
                    float4 w = w2g[(i4*4 + k)*32 + cqi];
                    float ax0 = (&at[0].x)[k], ax1 = (&at[1].x)[k];
                    float ax2 = (&at[2].x)[k], ax3 = (&at[3].x)[k];
                    acc[0].x += ax0*w.x; acc[0].y += ax0*w.y; acc[0].z += ax0*w.z; acc[0].w += ax0*w.w;
                    acc[1].x += ax1*w.x; acc[1].y += ax1*w.y; acc[1].z += ax1*w.z; acc[1].w += ax1*w.w;
                    acc[2].x += ax2*w.x; acc[2].y += ax2*w.y; acc[2].z += ax2*w.z; acc[2].w += ax2*w.w;
                    acc[3].x += ax3*w.x; acc[3].y += ax3*w.y; acc[3].z += ax3*w.z; acc[3].w += ax3*w.w;
                }
            }
            #pragma unroll
            for (int tl = 0; tl < 4; ++tl) {
                float* o = &outs[(17 + cqi*4)*OTS + tq*4 + tl];
                o[0*OTS] = fmaxf(acc[tl].x, 0.f);
                o[1*OTS] = fmaxf(acc[tl].y, 0.f);
                o[2*OTS] = fmaxf(acc[tl].z, 0.f);
                o[3*OTS] = fmaxf(acc[tl].w, 0.f);
            }
        }

        // ---- channels 0..16 (trunc x + time) -> LDS outtile
        for (int idx = tid; idx < 17*32; idx += 256) {
            int ch = idx >> 5, tt = idx & 31;
            int t = t0 + tt;
            float val = (ch < 16) ? xs[(l0 + tt + 2)*16 + ch] : (float)t * inv253;
            outs[ch*OTS + tt] = val;
        }
        __syncthreads();

        // ---- coalesced flush (t>=T garbage masked downstream)
        {
            const long nb = (long)n*A;
            for (int idx = tid; idx < A*32; idx += 256) {
                int row = idx >> 5, tt = idx & 31;
                aug_t[(nb + row)*TPAD + t0 + tt] = outs[row*OTS + tt];
            }
        }
        __syncthreads();
    }
}

// ---------------------------------------------------------------------------
// Kernel B: depth-2 signature via MFMA bf16-split GEMM.
// 2-pass coalesced staging; FIXED: per-pass basepoint a0a/a0b.
// ---------------------------------------------------------------------------
#define CHT 160
#define LDA2 40
#define RS 36

__global__ __launch_bounds__(256) void sig_kernel(
    const float* __restrict__ aug_t,
    unsigned short* __restrict__ sig_hi, unsigned short* __restrict__ sig_lo)
{
    __shared__ __align__(16) unsigned short MhT[CHT*LDA2];
    __shared__ __align__(16) unsigned short MlT[CHT*LDA2];
    __shared__ __align__(16) unsigned short DhT[CHT*LDA2];
    __shared__ __align__(16) unsigned short DlT[CHT*LDA2];
    __shared__ __align__(16) float rowsb[80*RS];   // 11.5KB; total 62.7KB

    const int tid = threadIdx.x;
    const int n = blockIdx.x;
    const float* an = aug_t + (long)n*A*TPAD;

    const int lane = tid & 63;
    const int w    = tid >> 6;
    const int wm   = w & 1;
    const int wn   = w >> 1;
    const int frow = lane & 15;
    const int quad = lane >> 4;

    // per-pass basepoints: pass0 channel = tid, pass1 channel = 80+tid
    const float a0a = (tid < A)      ? an[(long)tid*TPAD]        : 0.f;
    const float a0b = (tid < A - 80) ? an[(long)(80 + tid)*TPAD] : 0.f;

    // zero M/D rows 145..159 once
    if (tid >= A && tid < CHT) {
        const ushort8 z8v = {0,0,0,0,0,0,0,0};
        #pragma unroll
        for (int p = 0; p < 4; ++p) {
            *(ushort8*)&MhT[tid*LDA2 + p*8] = z8v;
            *(ushort8*)&MlT[tid*LDA2 + p*8] = z8v;
            *(ushort8*)&DhT[tid*LDA2 + p*8] = z8v;
            *(ushort8*)&DlT[tid*LDA2 + p*8] = z8v;
        }
    }

    floatx4 acc[5][5];
    #pragma unroll
    for (int i = 0; i < 5; ++i)
        #pragma unroll
        for (int j = 0; j < 5; ++j)
            acc[i][j] = (floatx4){0.f, 0.f, 0.f, 0.f};

    for (int c = 0; c < 8; ++c) {
        const int t0 = c*32;
        #pragma unroll 1
        for (int p = 0; p < 2; ++p) {
            const int r0 = p*80;
            const int rcnt = p ? (A - 80) : 80;   // 80 then 65
            // coalesced staging through rowsb
            for (int idx = tid; idx < rcnt*9; idx += 256) {
                int r = idx / 9, f4 = idx - r*9;
                const float* src = an + (long)(r0 + r)*TPAD + t0;
                if (f4 < 8) {
                    *(float4*)&rowsb[r*RS + f4*4] = *(const float4*)(src + f4*4);
                } else if (c < 7) {
                    *(float4*)&rowsb[r*RS + 32] = *(const float4*)(src + 32);
                }
            }
            __syncthreads();
            if (tid < rcnt) {
                const int chp = r0 + tid;
                const float a0p = p ? a0b : a0a;
                float v[33];
                #pragma unroll
                for (int i = 0; i < 8; ++i)
                    *(float4*)&v[i*4] = *(const float4*)&rowsb[tid*RS + i*4];
                v[32] = rowsb[tid*RS + 32];
                unsigned short mh[32], ml[32], dh[32], dl[32];
                #pragma unroll
                for (int tl = 0; tl < 32; ++tl) {
                    bool valid = (t0 + tl) <= 252;
                    float x0 = v[tl], x1 = v[tl+1];
                    float d = valid ? (x1 - x0) : 0.f;
                    float m = valid ? (0.5f*(x0 + x1) - a0p) : 0.f;
                    unsigned short hb = f2bf(m);
                    mh[tl] = hb; ml[tl] = f2bf(m - bf2f(hb));
                    unsigned short db2 = f2bf(d);
                    dh[tl] = db2; dl[tl] = f2bf(d - bf2f(db2));
                }
                #pragma unroll
                for (int pp = 0; pp < 4; ++pp) {
                    *(ushort8*)&MhT[chp*LDA2 + pp*8] = *(ushort8*)&mh[pp*8];
                    *(ushort8*)&MlT[chp*LDA2 + pp*8] = *(ushort8*)&ml[pp*8];
                    *(ushort8*)&DhT[chp*LDA2 + pp*8] = *(ushort8*)&dh[pp*8];
                    *(ushort8*)&DlT[chp*LDA2 + pp*8] = *(ushort8*)&dl[pp*8];
                }
            }
            __syncthreads();
        }

        short8 afh[5], afl[5], bfh[5], bfl[5];
        #pragma unroll
        for (int i = 0; i < 5; ++i) {
            int ar = (wm*80 + i*16 + frow)*LDA2 + quad*8;
            int br = (wn*80 + i*16 + frow)*LDA2 + quad*8;
            afh[i] = *(const short8*)&MhT[ar];
            afl[i] = *(const short8*)&MlT[ar];
            bfh[i] = *(const short8*)&DhT[br];
            bfl[i] = *(const short8*)&DlT[br];
        }
        #pragma unroll
        for (int mt = 0; mt < 5; ++mt)
            #pragma unroll
            for (int nt = 0; nt < 5; ++nt) {
                acc[mt][nt] = __builtin_amdgcn_mfma_f32_16x16x32_bf16(
                    afh[mt], bfh[nt], acc[mt][nt], 0, 0, 0);
                acc[mt][nt] = __builtin_amdgcn_mfma_f32_16x16x32_bf16(
                    afh[mt], bfl[nt], acc[mt][nt], 0, 0, 0);
                acc[mt][nt] = __builtin_amdgcn_mfma_f32_16x16x32_bf16(
                    afl[mt], bfh[nt], acc[mt][nt], 0, 0, 0);
            }
        __syncthreads();
    }

    // epilogue: compensated bf16 split of s1 and s2
    unsigned short* sh = sig_hi + (long)n*KP;
    unsigned short* sl = sig_lo + (long)n*KP;
    if (tid < A) {
        float v = an[(long)tid*TPAD + 253] - a0a;
        unsigned short hb = f2bf(v);
        sh[tid] = hb;
        sl[tid] = f2bf(v - bf2f(hb));
    }
    if (tid >= 160 && tid < 160 + (KP - SIG_CH)) {
        sh[SIG_CH + tid - 160] = 0;
        sl[SIG_CH + tid - 160] = 0;
    }
    #pragma unroll
    for (int mt = 0; mt < 5; ++mt)
        #pragma unroll
        for (int nt = 0; nt < 5; ++nt) {
            int j = wn*80 + nt*16 + frow;
            int ib = wm*80 + mt*16 + quad*4;
            #pragma unroll
            for (int e = 0; e < 4; ++e) {
                int i = ib + e;
                if (i < A && j < A) {
                    float v = acc[mt][nt][e];
                    unsigned short hb = f2bf(v);
                    sh[A + i*A + j] = hb;
                    sl[A + i*A + j] = f2bf(v - bf2f(hb));
                }
            }
        }
}

// ---------------------------------------------------------------------------
// Kernel W: W[k][o] fp32 -> Wt_hi/Wt_lo[o][KP] bf16 (transposed, split).
// Launched AFTER sig (wt_* overlays the then-dead aug_t region).
// ---------------------------------------------------------------------------
__global__ __launch_bounds__(256) void wconv_kernel(
    const float* __restrict__ W,
    unsigned short* __restrict__ wt_hi, unsigned short* __restrict__ wt_lo)
{
    __shared__ float ls[64][65];
    const int tid = threadIdx.x;
    const int k0 = blockIdx.x * 64;
    const int o0 = blockIdx.y * 64;

    #pragma unroll
    for (int p = 0; p < 16; ++p) {
        int idx = tid + p*256;
        int kk = idx >> 6, oo = idx & 63;
        int k = k0 + kk;
        ls[kk][oo] = (k < SIG_CH) ? W[(long)k*OUT + o0 + oo] : 0.f;
    }
    __syncthreads();

    const int oo = tid >> 2;
    const int kq = (tid & 3) * 16;
    unsigned short hbuf[16], lbuf[16];
    #pragma unroll
    for (int j = 0; j < 16; ++j) {
        float v = ls[kq + j][oo];
        unsigned short hb = f2bf(v);
        hbuf[j] = hb;
        lbuf[j] = f2bf(v - bf2f(hb));
    }
    long off = (long)(o0 + oo)*KP + k0 + kq;
    *(ushort8*)(wt_hi + off)     = *(ushort8*)&hbuf[0];
    *(ushort8*)(wt_hi + off + 8) = *(ushort8*)&hbuf[8];
    *(ushort8*)(wt_lo + off)     = *(ushort8*)&lbuf[0];
    *(ushort8*)(wt_lo + off + 8) = *(ushort8*)&lbuf[8];
}

// ---------------------------------------------------------------------------
// Kernel C: MFMA bf16 split GEMM. part[z] = sig * Wt^T over K-chunk.
// ---------------------------------------------------------------------------
#define SPLITK 61
#define KC 352
#define NSTEP (KC/32)   // 11
#define LDA 40

__global__ __launch_bounds__(256) void gemm_kernel(
    const unsigned short* __restrict__ sig_hi, const unsigned short* __restrict__ sig_lo,
    const unsigned short* __restrict__ wt_hi,  const unsigned short* __restrict__ wt_lo,
    float* __restrict__ part)
{
    __shared__ __align__(16) unsigned short Ah[128*LDA];
    __shared__ __align__(16) unsigned short Al[128*LDA];
    __shared__ __align__(16) unsigned short Bh[128*LDA];
    __shared__ __align__(16) unsigned short Bl[128*LDA];

    const int tid = threadIdx.x;
    const int o0 = blockIdx.x * 128;
    const int n0 = blockIdx.y * 128;
    const int z  = blockIdx.z;
    const int k0 = z * KC;

    const int lane = tid & 63;
    const int w    = tid >> 6;
    const int wm   = w & 1;
    const int wn   = w >> 1;
    const int frow = lane & 15;
    const int quad = lane >> 4;

    const int srow = tid >> 1;
    const int kh   = (tid & 1) * 16;

    const unsigned short* gAh = sig_hi + (long)(n0 + srow)*KP;
    const unsigned short* gAl = sig_lo + (long)(n0 + srow)*KP;
    const unsigned short* gBh = wt_hi  + (long)(o0 + srow)*KP;
    const unsigned short* gBl = wt_lo  + (long)(o0 + srow)*KP;

    ushort8 rah[2], ral[2], rbh[2], rbl[2];
    const ushort8 z8 = {0,0,0,0,0,0,0,0};

    #define GLOAD(s)                                                          \
        {                                                                     \
            int kb = k0 + (s)*32 + kh;                                        \
            if (kb < KP) {                                                    \
                rah[0] = *(const ushort8*)(gAh + kb);                         \
                rah[1] = *(const ushort8*)(gAh + kb + 8);                     \
                ral[0] = *(const ushort8*)(gAl + kb);                         \
                ral[1] = *(const ushort8*)(gAl + kb + 8);                     \
                rbh[0] = *(const ushort8*)(gBh + kb);                         \
                rbh[1] = *(const ushort8*)(gBh + kb + 8);                     \
                rbl[0] = *(const ushort8*)(gBl + kb);                         \
                rbl[1] = *(const ushort8*)(gBl + kb + 8);                     \
            } else {                                                          \
                rah[0]=z8; rah[1]=z8; ral[0]=z8; ral[1]=z8;                   \
                rbh[0]=z8; rbh[1]=z8; rbl[0]=z8; rbl[1]=z8;                   \
            }                                                                 \
        }

    #define LSTORE()                                                          \
        {                                                                     \
            int o = srow*LDA + kh;                                            \
            *(ushort8*)(Ah + o)     = rah[0];                                 \
            *(ushort8*)(Ah + o + 8) = rah[1];                                 \
            *(ushort8*)(Al + o)     = ral[0];                                 \
            *(ushort8*)(Al + o + 8) = ral[1];                                 \
            *(ushort8*)(Bh + o)     = rbh[0];                                 \
            *(ushort8*)(Bh + o + 8) = rbh[1];                                 \
            *(ushort8*)(Bl + o)     = rbl[0];                                 \
            *(ushort8*)(Bl + o + 8) = rbl[1];                                 \
        }

    floatx4 acc[4][4];
    #pragma unroll
    for (int i = 0; i < 4; ++i)
        #pragma unroll
        for (int j = 0; j < 4; ++j)
            acc[i][j] = (floatx4){0.f, 0.f, 0.f, 0.f};

    GLOAD(0);
    LSTORE();
    __syncthreads();

    for (int s = 0; s < NSTEP; ++s) {
        if (s < NSTEP-1) GLOAD(s+1);

        short8 afh[4], afl[4], bfh[4], bfl[4];
        const int aoff = (wm*64 + frow)*LDA + quad*8;
        const int boff = (wn*64 + frow)*LDA + quad*8;
        #pragma unroll
        for (int tI = 0; tI < 4; ++tI) {
            afh[tI] = *(const short8*)(Ah + aoff + tI*16*LDA);
            afl[tI] = *(const short8*)(Al + aoff + tI*16*LDA);
            bfh[tI] = *(const short8*)(Bh + boff + tI*16*LDA);
            bfl[tI] = *(const short8*)(Bl + boff + tI*16*LDA);
        }
        #pragma unroll
        for (int mt = 0; mt < 4; ++mt)
            #pragma unroll
            for (int nt = 0; nt < 4; ++nt) {
                acc[mt][nt] = __builtin_amdgcn_mfma_f32_16x16x32_bf16(
                    afh[mt], bfh[nt], acc[mt][nt], 0, 0, 0);
                acc[mt][nt] = __builtin_amdgcn_mfma_f32_16x16x32_bf16(
                    afh[mt], bfl[nt], acc[mt][nt], 0, 0, 0);
                acc[mt][nt] = __builtin_amdgcn_mfma_f32_16x16x32_bf16(
                    afl[mt], bfh[nt], acc[mt][nt], 0, 0, 0);
            }
        __syncthreads();
        if (s < NSTEP-1) {
            LSTORE();
            __syncthreads();
        }
    }

    float* pz = part + (long)z * (Nn*OUT);
    #pragma unroll
    for (int mt = 0; mt < 4; ++mt)
        #pragma unroll
        for (int nt = 0; nt < 4; ++nt) {
            int col = o0 + wn*64 + nt*16 + frow;
            int rbase = n0 + wm*64 + mt*16 + quad*4;
            #pragma unroll
            for (int e = 0; e < 4; ++e)
                pz[(long)(rbase + e)*OUT + col] = acc[mt][nt][e];
        }
}

// ---------------------------------------------------------------------------
// Kernel D: out[n][o] = lin_b[o] + sum_z part[z][n][o]
// ---------------------------------------------------------------------------
__global__ __launch_bounds__(256) void reduce_kernel(
    const float* __restrict__ part, const float* __restrict__ lb,
    float* __restrict__ out)
{
    int idx = blockIdx.x * 256 + threadIdx.x;
    float s = lb[idx & 255];
    #pragma unroll 8
    for (int z = 0; z < SPLITK; ++z)
        s += part[(long)z * (Nn*OUT) + idx];
    out[idx] = s;
}

// ---------------------------------------------------------------------------
extern "C" void kernel_launch(void* const* d_in, const int* in_sizes, int n_in,
                              void* d_out, int out_size, void* d_ws, size_t ws_size,
                              hipStream_t stream) {
    const float* q  = (const float*)d_in[0];
    const float* w1 = (const float*)d_in[4];
    const float* b1 = (const float*)d_in[5];
    const float* w2 = (const float*)d_in[6];
    const float* b2 = (const float*)d_in[7];
    const float* lw = (const float*)d_in[8];
    const float* lb = (const float*)d_in[9];
    float* out = (float*)d_out;

    // ws layout — PROVEN 59.71 MB envelope (identical to R9):
    //   [0]          sig_hi  (10,846,208)
    //   [10846208]   sig_lo  (10,846,208)
    //   [21692416]   aug_t fp32 [256][145][256] (38,010,880)
    //     aug_t dead after sig_kernel; region then reused (stream-ordered):
    //     [21692416] wt_hi (10,846,208)
    //     [32538624] wt_lo (10,846,208)
    //     [43384832] part  (15,990,784)   ends 59,375,616
    char* ws = (char*)d_ws;
    unsigned short* sig_hi = (unsigned short*)ws;
    unsigned short* sig_lo = (unsigned short*)(ws + 10846208);
    float*          aug_t  = (float*)(ws + 21692416);
    unsigned short* wt_hi  = (unsigned short*)(ws + 21692416);
    unsigned short* wt_lo  = (unsigned short*)(ws + 32538624);
    float*          part   = (float*)(ws + 43384832);

    aug_kernel<<<dim3(4, Nn), 256, 0, stream>>>(q, w1, b1, w2, b2, aug_t);
    sig_kernel<<<Nn, 256, 0, stream>>>(aug_t, sig_hi, sig_lo);
    wconv_kernel<<<dim3(KP/64, OUT/64), 256, 0, stream>>>(lw, wt_hi, wt_lo);
    gemm_kernel<<<dim3(2, 2, SPLITK), 256, 0, stream>>>(sig_hi, sig_lo, wt_hi, wt_lo, part);
    reduce_kernel<<<(Nn*OUT)/256, 256, 0, stream>>>(part, lb, out);
}

// Round 12
// 194.788 us; speedup vs baseline: 1.1295x; 1.1295x over previous
//
#include <hip/hip_runtime.h>
#include <hip/hip_bf16.h>

// Problem constants
#define Bq 32
#define Lq 256
#define Hq 8
#define Eq 16
#define Nn (Bq*Hq)        // 256 sequences
#define T 254             // Lq - 3 + 1
#define A 145             // E + 1 + 128 augmented channels
#define SIG_CH (A + A*A)  // 21170
#define KP 21184          // padded K (mult of 32), bf16 arrays
#define OUT 256
#define TPAD 256          // aug_t row stride (t dimension)
#define OTS 35            // outtile LDS row stride (floats)

typedef __attribute__((ext_vector_type(8))) short short8;
typedef __attribute__((ext_vector_type(8))) unsigned short ushort8;
typedef __attribute__((ext_vector_type(4))) float floatx4;

static __device__ __forceinline__ unsigned short f2bf(float v) {
    unsigned int u = __float_as_uint(v);
    unsigned int r = (u + 0x7FFFu + ((u >> 16) & 1u)) >> 16;
    return (unsigned short)r;
}
static __device__ __forceinline__ float bf2f(unsigned short b) {
    return __uint_as_float(((unsigned int)b) << 16);
}

// ---------------------------------------------------------------------------
// Kernel A: conv1(k=3,16->64) -> conv2(k=1,64->128)+ReLU -> aug_t[n][ch][t].
// grid (4, 256), 256 threads. (R11 form, kept.)
// ---------------------------------------------------------------------------
__global__ __launch_bounds__(256) void aug_kernel(
    const float* __restrict__ q,
    const float* __restrict__ w1, const float* __restrict__ b1,
    const float* __restrict__ w2, const float* __restrict__ b2,
    float* __restrict__ aug_t)
{
    __shared__ __align__(16) float w1s[48*64];    // 12KB
    __shared__ __align__(16) float b1s[64];
    __shared__ __align__(16) float b2s[128];
    __shared__ __align__(16) float xs[68*16];     // 4.35KB
    __shared__ __align__(16) float a1s[32*64];    // 8KB
    __shared__ __align__(16) float outs[A*OTS];   // 20.3KB

    const int tid = threadIdx.x;
    const int n = blockIdx.y;
    const int b = n >> 3, h = n & 7;
    const int tb0 = blockIdx.x * 64;

    for (int i = tid; i < 48*64; i += 256) w1s[i] = w1[i];
    if (tid < 64)  b1s[tid] = b1[tid];
    if (tid < 128) b2s[tid] = b2[tid];
    {
        const float4* q4 = (const float4*)q + ((long)(b*Lq)*Hq + h)*4;
        float4* xs4 = (float4*)xs;
        for (int i = tid; i < 68*4; i += 256) {
            int rr = i >> 2, e4 = i & 3;
            int t = tb0 + rr; if (t > 255) t = 255;
            xs4[rr*4 + e4] = q4[t*32 + e4];
        }
    }
    __syncthreads();

    const float inv253 = 1.0f / 253.0f;
    const float4* w2g = (const float4*)w2;   // [i][c/4]

    #pragma unroll
    for (int sub = 0; sub < 2; ++sub) {
        const int t0 = tb0 + sub*32;
        const int l0 = sub*32;

        // ---- conv1: thread = (c-quad, t rows tg & tg+16)
        {
            const int c = (tid & 15) * 4;
            const int tg = tid >> 4;
            float4 bb = *(const float4*)&b1s[c];
            float4 acc0 = bb, acc1 = bb;
            #pragma unroll 1
            for (int dt = 0; dt < 3; ++dt) {
                const float* xra = &xs[(l0 + tg + dt)*16];
                const float* xrb = &xs[(l0 + tg + 16 + dt)*16];
                #pragma unroll
                for (int i4 = 0; i4 < 4; ++i4) {
                    float4 xa = *(const float4*)(xra + i4*4);
                    float4 xb = *(const float4*)(xrb + i4*4);
                    const float* wb = &w1s[(dt*16 + i4*4)*64 + c];
                    float4 w0 = *(const float4*)(wb);
                    float4 wv1 = *(const float4*)(wb + 64);
                    float4 wv2 = *(const float4*)(wb + 128);
                    float4 w3 = *(const float4*)(wb + 192);
                    acc0.x += xa.x*w0.x + xa.y*wv1.x + xa.z*wv2.x + xa.w*w3.x;
                    acc0.y += xa.x*w0.y + xa.y*wv1.y + xa.z*wv2.y + xa.w*w3.y;
                    acc0.z += xa.x*w0.z + xa.y*wv1.z + xa.z*wv2.z + xa.w*w3.z;
                    acc0.w += xa.x*w0.w + xa.y*wv1.w + xa.z*wv2.w + xa.w*w3.w;
                    acc1.x += xb.x*w0.x + xb.y*wv1.x + xb.z*wv2.x + xb.w*w3.x;
                    acc1.y += xb.x*w0.y + xb.y*wv1.y + xb.z*wv2.y + xb.w*w3.y;
                    acc1.z += xb.x*w0.z + xb.y*wv1.z + xb.z*wv2.z + xb.w*w3.z;
                    acc1.w += xb.x*w0.w + xb.y*wv1.w + xb.z*wv2.w + xb.w*w3.w;
                }
            }
            *(float4*)&a1s[(tid >> 4)*64 + c]        = acc0;
            *(float4*)&a1s[((tid >> 4) + 16)*64 + c] = acc1;
        }
        __syncthreads();

        // ---- conv2 + ReLU -> LDS outtile (b128 a1s reads, broadcast)
        {
            const int cqi = tid & 31;
            const int tq  = tid >> 5;
            float4 bb = *(const float4*)&b2s[cqi*4];
            float4 acc[4] = {bb, bb, bb, bb};
            #pragma unroll 2
            for (int i4 = 0; i4 < 16; ++i4) {
                float4 at[4];
                #pragma unroll
                for (int tl = 0; tl < 4; ++tl)
                    at[tl] = *(const float4*)&a1s[(tq*4 + tl)*64 + i4*4];
                #pragma unroll
                for (int k = 0; k < 4; ++k) {
                    float4 w = w2g[(i4*4 + k)*32 + cqi];
                    float ax0 = (&at[0].x)[k], ax1 = (&at[1].x)[k];
                    float ax2 = (&at[2].x)[k], ax3 = (&at[3].x)[k];
                    acc[0].x += ax0*w.x; acc[0].y += ax0*w.y; acc[0].z += ax0*w.z; acc[0].w += ax0*w.w;
                    acc[1].x += ax1*w.x; acc[1].y += ax1*w.y; acc[1].z += ax1*w.z; acc[1].w += ax1*w.w;
                    acc[2].x += ax2*w.x; acc[2].y += ax2*w.y; acc[2].z += ax2*w.z; acc[2].w += ax2*w.w;
                    acc[3].x += ax3*w.x; acc[3].y += ax3*w.y; acc[3].z += ax3*w.z; acc[3].w += ax3*w.w;
                }
            }
            #pragma unroll
            for (int tl = 0; tl < 4; ++tl) {
                float* o = &outs[(17 + cqi*4)*OTS + tq*4 + tl];
                o[0*OTS] = fmaxf(acc[tl].x, 0.f);
                o[1*OTS] = fmaxf(acc[tl].y, 0.f);
                o[2*OTS] = fmaxf(acc[tl].z, 0.f);
                o[3*OTS] = fmaxf(acc[tl].w, 0.f);
            }
        }

        // ---- channels 0..16 (trunc x + time) -> LDS outtile
        for (int idx = tid; idx < 17*32; idx += 256) {
            int ch = idx >> 5, tt = idx & 31;
            int t = t0 + tt;
            float val = (ch < 16) ? xs[(l0 + tt + 2)*16 + ch] : (float)t * inv253;
            outs[ch*OTS + tt] = val;
        }
        __syncthreads();

        // ---- coalesced flush (t>=T garbage masked downstream)
        {
            const long nb = (long)n*A;
            for (int idx = tid; idx < A*32; idx += 256) {
                int row = idx >> 5, tt = idx & 31;
                aug_t[(nb + row)*TPAD + t0 + tt] = outs[row*OTS + tt];
            }
        }
        __syncthreads();
    }
}

// ---------------------------------------------------------------------------
// Kernel B: depth-2 signature via MFMA bf16-split GEMM.
// REVERTED to the R6/R9-proven form: direct per-thread global reads,
// single pack pass (ch = tid), 51.2KB LDS, 2 barriers per K-chunk.
// ---------------------------------------------------------------------------
#define CHT 160
#define LDA2 40

__global__ __launch_bounds__(256) void sig_kernel(
    const float* __restrict__ aug_t,
    unsigned short* __restrict__ sig_hi, unsigned short* __restrict__ sig_lo)
{
    __shared__ __align__(16) unsigned short MhT[CHT*LDA2];
    __shared__ __align__(16) unsigned short MlT[CHT*LDA2];
    __shared__ __align__(16) unsigned short DhT[CHT*LDA2];
    __shared__ __align__(16) unsigned short DlT[CHT*LDA2];

    const int tid = threadIdx.x;
    const int n = blockIdx.x;
    const float* an = aug_t + (long)n*A*TPAD;

    const int lane = tid & 63;
    const int w    = tid >> 6;
    const int wm   = w & 1;
    const int wn   = w >> 1;
    const int frow = lane & 15;
    const int quad = lane >> 4;

    const int ch = tid;   // staging row for tid < CHT
    float a0 = 0.f;
    if (ch < A) a0 = an[(long)ch*TPAD];

    floatx4 acc[5][5];
    #pragma unroll
    for (int i = 0; i < 5; ++i)
        #pragma unroll
        for (int j = 0; j < 5; ++j)
            acc[i][j] = (floatx4){0.f, 0.f, 0.f, 0.f};

    for (int c = 0; c < 8; ++c) {
        const int t0 = c*32;
        if (ch < CHT) {
            unsigned short mh[32], ml[32], dh[32], dl[32];
            if (ch < A) {
                float v[33];
                const float* src = an + (long)ch*TPAD + t0;
                #pragma unroll
                for (int i = 0; i < 8; ++i)
                    *(float4*)&v[i*4] = *(const float4*)(src + i*4);
                v[32] = (t0 + 32 <= 253) ? src[32] : 0.f;
                #pragma unroll
                for (int tl = 0; tl < 32; ++tl) {
                    bool valid = (t0 + tl) <= 252;
                    float x0 = v[tl], x1 = v[tl+1];
                    float d = valid ? (x1 - x0) : 0.f;
                    float m = valid ? (0.5f*(x0 + x1) - a0) : 0.f;
                    unsigned short hb = f2bf(m);
                    mh[tl] = hb; ml[tl] = f2bf(m - bf2f(hb));
                    unsigned short db2 = f2bf(d);
                    dh[tl] = db2; dl[tl] = f2bf(d - bf2f(db2));
                }
            } else {
                #pragma unroll
                for (int tl = 0; tl < 32; ++tl) { mh[tl]=0; ml[tl]=0; dh[tl]=0; dl[tl]=0; }
            }
            #pragma unroll
            for (int p = 0; p < 4; ++p) {
                *(ushort8*)&MhT[ch*LDA2 + p*8] = *(ushort8*)&mh[p*8];
                *(ushort8*)&MlT[ch*LDA2 + p*8] = *(ushort8*)&ml[p*8];
                *(ushort8*)&DhT[ch*LDA2 + p*8] = *(ushort8*)&dh[p*8];
                *(ushort8*)&DlT[ch*LDA2 + p*8] = *(ushort8*)&dl[p*8];
            }
        }
        __syncthreads();

        short8 afh[5], afl[5], bfh[5], bfl[5];
        #pragma unroll
        for (int i = 0; i < 5; ++i) {
            int ar = (wm*80 + i*16 + frow)*LDA2 + quad*8;
            int br = (wn*80 + i*16 + frow)*LDA2 + quad*8;
            afh[i] = *(const short8*)&MhT[ar];
            afl[i] = *(const short8*)&MlT[ar];
            bfh[i] = *(const short8*)&DhT[br];
            bfl[i] = *(const short8*)&DlT[br];
        }
        #pragma unroll
        for (int mt = 0; mt < 5; ++mt)
            #pragma unroll
            for (int nt = 0; nt < 5; ++nt) {
                acc[mt][nt] = __builtin_amdgcn_mfma_f32_16x16x32_bf16(
                    afh[mt], bfh[nt], acc[mt][nt], 0, 0, 0);
                acc[mt][nt] = __builtin_amdgcn_mfma_f32_16x16x32_bf16(
                    afh[mt], bfl[nt], acc[mt][nt], 0, 0, 0);
                acc[mt][nt] = __builtin_amdgcn_mfma_f32_16x16x32_bf16(
                    afl[mt], bfh[nt], acc[mt][nt], 0, 0, 0);
            }
        __syncthreads();
    }

    // epilogue: compensated bf16 split of s1 and s2
    unsigned short* sh = sig_hi + (long)n*KP;
    unsigned short* sl = sig_lo + (long)n*KP;
    if (tid < A) {
        float v = an[(long)tid*TPAD + 253] - a0;
        unsigned short hb = f2bf(v);
        sh[tid] = hb;
        sl[tid] = f2bf(v - bf2f(hb));
    }
    if (tid >= 160 && tid < 160 + (KP - SIG_CH)) {
        sh[SIG_CH + tid - 160] = 0;
        sl[SIG_CH + tid - 160] = 0;
    }
    #pragma unroll
    for (int mt = 0; mt < 5; ++mt)
        #pragma unroll
        for (int nt = 0; nt < 5; ++nt) {
            int j = wn*80 + nt*16 + frow;
            int ib = wm*80 + mt*16 + quad*4;
            #pragma unroll
            for (int e = 0; e < 4; ++e) {
                int i = ib + e;
                if (i < A && j < A) {
                    float v = acc[mt][nt][e];
                    unsigned short hb = f2bf(v);
                    sh[A + i*A + j] = hb;
                    sl[A + i*A + j] = f2bf(v - bf2f(hb));
                }
            }
        }
}

// ---------------------------------------------------------------------------
// Kernel W: W[k][o] fp32 -> Wt_hi/Wt_lo[o][KP] bf16 (transposed, split).
// ---------------------------------------------------------------------------
__global__ __launch_bounds__(256) void wconv_kernel(
    const float* __restrict__ W,
    unsigned short* __restrict__ wt_hi, unsigned short* __restrict__ wt_lo)
{
    __shared__ float ls[64][65];
    const int tid = threadIdx.x;
    const int k0 = blockIdx.x * 64;
    const int o0 = blockIdx.y * 64;

    #pragma unroll
    for (int p = 0; p < 16; ++p) {
        int idx = tid + p*256;
        int kk = idx >> 6, oo = idx & 63;
        int k = k0 + kk;
        ls[kk][oo] = (k < SIG_CH) ? W[(long)k*OUT + o0 + oo] : 0.f;
    }
    __syncthreads();

    const int oo = tid >> 2;
    const int kq = (tid & 3) * 16;
    unsigned short hbuf[16], lbuf[16];
    #pragma unroll
    for (int j = 0; j < 16; ++j) {
        float v = ls[kq + j][oo];
        unsigned short hb = f2bf(v);
        hbuf[j] = hb;
        lbuf[j] = f2bf(v - bf2f(hb));
    }
    long off = (long)(o0 + oo)*KP + k0 + kq;
    *(ushort8*)(wt_hi + off)     = *(ushort8*)&hbuf[0];
    *(ushort8*)(wt_hi + off + 8) = *(ushort8*)&hbuf[8];
    *(ushort8*)(wt_lo + off)     = *(ushort8*)&lbuf[0];
    *(ushort8*)(wt_lo + off + 8) = *(ushort8*)&lbuf[8];
}

// ---------------------------------------------------------------------------
// Kernel C: MFMA bf16 split GEMM. part[z] = sig * Wt^T over K-chunk.
// ---------------------------------------------------------------------------
#define SPLITK 61
#define KC 352
#define NSTEP (KC/32)   // 11
#define LDA 40

__global__ __launch_bounds__(256) void gemm_kernel(
    const unsigned short* __restrict__ sig_hi, const unsigned short* __restrict__ sig_lo,
    const unsigned short* __restrict__ wt_hi,  const unsigned short* __restrict__ wt_lo,
    float* __restrict__ part)
{
    __shared__ __align__(16) unsigned short Ah[128*LDA];
    __shared__ __align__(16) unsigned short Al[128*LDA];
    __shared__ __align__(16) unsigned short Bh[128*LDA];
    __shared__ __align__(16) unsigned short Bl[128*LDA];

    const int tid = threadIdx.x;
    const int o0 = blockIdx.x * 128;
    const int n0 = blockIdx.y * 128;
    const int z  = blockIdx.z;
    const int k0 = z * KC;

    const int lane = tid & 63;
    const int w    = tid >> 6;
    const int wm   = w & 1;
    const int wn   = w >> 1;
    const int frow = lane & 15;
    const int quad = lane >> 4;

    const int srow = tid >> 1;
    const int kh   = (tid & 1) * 16;

    const unsigned short* gAh = sig_hi + (long)(n0 + srow)*KP;
    const unsigned short* gAl = sig_lo + (long)(n0 + srow)*KP;
    const unsigned short* gBh = wt_hi  + (long)(o0 + srow)*KP;
    const unsigned short* gBl = wt_lo  + (long)(o0 + srow)*KP;

    ushort8 rah[2], ral[2], rbh[2], rbl[2];
    const ushort8 z8 = {0,0,0,0,0,0,0,0};

    #define GLOAD(s)                                                          \
        {                                                                     \
            int kb = k0 + (s)*32 + kh;                                        \
            if (kb < KP) {                                                    \
                rah[0] = *(const ushort8*)(gAh + kb);                         \
                rah[1] = *(const ushort8*)(gAh + kb + 8);                     \
                ral[0] = *(const ushort8*)(gAl + kb);                         \
                ral[1] = *(const ushort8*)(gAl + kb + 8);                     \
                rbh[0] = *(const ushort8*)(gBh + kb);                         \
                rbh[1] = *(const ushort8*)(gBh + kb + 8);                     \
                rbl[0] = *(const ushort8*)(gBl + kb);                         \
                rbl[1] = *(const ushort8*)(gBl + kb + 8);                     \
            } else {                                                          \
                rah[0]=z8; rah[1]=z8; ral[0]=z8; ral[1]=z8;                   \
                rbh[0]=z8; rbh[1]=z8; rbl[0]=z8; rbl[1]=z8;                   \
            }                                                                 \
        }

    #define LSTORE()                                                          \
        {                                                                     \
            int o = srow*LDA + kh;                                            \
            *(ushort8*)(Ah + o)     = rah[0];                                 \
            *(ushort8*)(Ah + o + 8) = rah[1];                                 \
            *(ushort8*)(Al + o)     = ral[0];                                 \
            *(ushort8*)(Al + o + 8) = ral[1];                                 \
            *(ushort8*)(Bh + o)     = rbh[0];                                 \
            *(ushort8*)(Bh + o + 8) = rbh[1];                                 \
            *(ushort8*)(Bl + o)     = rbl[0];                                 \
            *(ushort8*)(Bl + o + 8) = rbl[1];                                 \
        }

    floatx4 acc[4][4];
    #pragma unroll
    for (int i = 0; i < 4; ++i)
        #pragma unroll
        for (int j = 0; j < 4; ++j)
            acc[i][j] = (floatx4){0.f, 0.f, 0.f, 0.f};

    GLOAD(0);
    LSTORE();
    __syncthreads();

    for (int s = 0; s < NSTEP; ++s) {
        if (s < NSTEP-1) GLOAD(s+1);

        short8 afh[4], afl[4], bfh[4], bfl[4];
        const int aoff = (wm*64 + frow)*LDA + quad*8;
        const int boff = (wn*64 + frow)*LDA + quad*8;
        #pragma unroll
        for (int tI = 0; tI < 4; ++tI) {
            afh[tI] = *(const short8*)(Ah + aoff + tI*16*LDA);
            afl[tI] = *(const short8*)(Al + aoff + tI*16*LDA);
            bfh[tI] = *(const short8*)(Bh + boff + tI*16*LDA);
            bfl[tI] = *(const short8*)(Bl + boff + tI*16*LDA);
        }
        #pragma unroll
        for (int mt = 0; mt < 4; ++mt)
            #pragma unroll
            for (int nt = 0; nt < 4; ++nt) {
                acc[mt][nt] = __builtin_amdgcn_mfma_f32_16x16x32_bf16(
                    afh[mt], bfh[nt], acc[mt][nt], 0, 0, 0);
                acc[mt][nt] = __builtin_amdgcn_mfma_f32_16x16x32_bf16(
                    afh[mt], bfl[nt], acc[mt][nt], 0, 0, 0);
                acc[mt][nt] = __builtin_amdgcn_mfma_f32_16x16x32_bf16(
                    afl[mt], bfh[nt], acc[mt][nt], 0, 0, 0);
            }
        __syncthreads();
        if (s < NSTEP-1) {
            LSTORE();
            __syncthreads();
        }
    }

    float* pz = part + (long)z * (Nn*OUT);
    #pragma unroll
    for (int mt = 0; mt < 4; ++mt)
        #pragma unroll
        for (int nt = 0; nt < 4; ++nt) {
            int col = o0 + wn*64 + nt*16 + frow;
            int rbase = n0 + wm*64 + mt*16 + quad*4;
            #pragma unroll
            for (int e = 0; e < 4; ++e)
                pz[(long)(rbase + e)*OUT + col] = acc[mt][nt][e];
        }
}

// ---------------------------------------------------------------------------
// Kernel D: out[n][o] = lin_b[o] + sum_z part[z][n][o]
// ---------------------------------------------------------------------------
__global__ __launch_bounds__(256) void reduce_kernel(
    const float* __restrict__ part, const float* __restrict__ lb,
    float* __restrict__ out)
{
    int idx = blockIdx.x * 256 + threadIdx.x;
    float s = lb[idx & 255];
    #pragma unroll 8
    for (int z = 0; z < SPLITK; ++z)
        s += part[(long)z * (Nn*OUT) + idx];
    out[idx] = s;
}

// ---------------------------------------------------------------------------
extern "C" void kernel_launch(void* const* d_in, const int* in_sizes, int n_in,
                              void* d_out, int out_size, void* d_ws, size_t ws_size,
                              hipStream_t stream) {
    const float* q  = (const float*)d_in[0];
    const float* w1 = (const float*)d_in[4];
    const float* b1 = (const float*)d_in[5];
    const float* w2 = (const float*)d_in[6];
    const float* b2 = (const float*)d_in[7];
    const float* lw = (const float*)d_in[8];
    const float* lb = (const float*)d_in[9];
    float* out = (float*)d_out;

    // ws layout — PROVEN 59.71 MB envelope:
    //   [0]          sig_hi  (10,846,208)
    //   [10846208]   sig_lo  (10,846,208)
    //   [21692416]   aug_t fp32 [256][145][256] (38,010,880)
    //     aug_t dead after sig_kernel; region then reused (stream-ordered):
    //     [21692416] wt_hi (10,846,208)
    //     [32538624] wt_lo (10,846,208)
    //     [43384832] part  (15,990,784)   ends 59,375,616
    char* ws = (char*)d_ws;
    unsigned short* sig_hi = (unsigned short*)ws;
    unsigned short* sig_lo = (unsigned short*)(ws + 10846208);
    float*          aug_t  = (float*)(ws + 21692416);
    unsigned short* wt_hi  = (unsigned short*)(ws + 21692416);
    unsigned short* wt_lo  = (unsigned short*)(ws + 32538624);
    float*          part   = (float*)(ws + 43384832);

    aug_kernel<<<dim3(4, Nn), 256, 0, stream>>>(q, w1, b1, w2, b2, aug_t);
    sig_kernel<<<Nn, 256, 0, stream>>>(aug_t, sig_hi, sig_lo);
    wconv_kernel<<<dim3(KP/64, OUT/64), 256, 0, stream>>>(lw, wt_hi, wt_lo);
    gemm_kernel<<<dim3(2, 2, SPLITK), 256, 0, stream>>>(sig_hi, sig_lo, wt_hi, wt_lo, part);
    reduce_kernel<<<(Nn*OUT)/256, 256, 0, stream>>>(part, lb, out);
}

// Round 13
// 181.076 us; speedup vs baseline: 1.2150x; 1.0757x over previous
//
#include <hip/hip_runtime.h>
#include <hip/hip_bf16.h>

// Problem constants
#define Bq 32
#define Lq 256
#define Hq 8
#define Eq 16
#define Nn (Bq*Hq)        // 256 sequences
#define T 254             // Lq - 3 + 1
#define A 145             // E + 1 + 128 augmented channels
#define SIG_CH (A + A*A)  // 21170
#define KP 21184          // padded K (mult of 32), bf16 arrays
#define OUT 256
#define TPAD 256          // aug_t row stride (t dimension)
#define OTS2 36           // outs LDS row stride (floats, 144B = 16B-mult)
#define XAS 72            // xim/a1 LDS row stride (ushorts, 144B)

typedef __attribute__((ext_vector_type(8))) short short8;
typedef __attribute__((ext_vector_type(8))) unsigned short ushort8;
typedef __attribute__((ext_vector_type(4))) float floatx4;

static __device__ __forceinline__ unsigned short f2bf(float v) {
    unsigned int u = __float_as_uint(v);
    unsigned int r = (u + 0x7FFFu + ((u >> 16) & 1u)) >> 16;
    return (unsigned short)r;
}
static __device__ __forceinline__ float bf2f(unsigned short b) {
    return __uint_as_float(((unsigned int)b) << 16);
}

// ---------------------------------------------------------------------------
// Kernel P: weight prep. w1[48][64] -> w1im[c=64][k=64 pad0] bf16 hi/lo;
// w2[64][128] -> w2t[c=128][i=64] bf16 hi/lo. grid(48) x 256.
// ---------------------------------------------------------------------------
__global__ __launch_bounds__(256) void wsplit_kernel(
    const float* __restrict__ w1, const float* __restrict__ w2,
    unsigned short* __restrict__ w1im_hi, unsigned short* __restrict__ w1im_lo,
    unsigned short* __restrict__ w2t_hi,  unsigned short* __restrict__ w2t_lo)
{
    int idx = blockIdx.x*256 + threadIdx.x;   // 0..12287
    if (idx < 4096) {
        int c = idx & 63, k = idx >> 6;       // k 0..63
        float v = (k < 48) ? w1[k*64 + c] : 0.f;
        unsigned short hb = f2bf(v);
        w1im_hi[c*64 + k] = hb;
        w1im_lo[c*64 + k] = f2bf(v - bf2f(hb));
    } else {
        int j = idx - 4096;                   // 0..8191
        int c = j & 127, i = j >> 7;          // i 0..63
        float v = w2[i*128 + c];
        unsigned short hb = f2bf(v);
        w2t_hi[c*64 + i] = hb;
        w2t_lo[c*64 + i] = f2bf(v - bf2f(hb));
    }
}

// ---------------------------------------------------------------------------
// Kernel A: MFMA convs. conv1 (32t x 64c, K=48 im2col, padded 64) and
// conv2 (32t x 128c, K=64) as bf16-split MFMA GEMMs; B-frags from global
// (w1im/w2t, L2-hot). Output aug_t[n][ch][t] via LDS outtile + coalesced
// flush. grid (4, 256), 256 threads = 4 waves.
// ---------------------------------------------------------------------------
__global__ __launch_bounds__(256) void aug_kernel(
    const float* __restrict__ q,
    const float* __restrict__ b1, const float* __restrict__ b2,
    const unsigned short* __restrict__ w1im_hi, const unsigned short* __restrict__ w1im_lo,
    const unsigned short* __restrict__ w2t_hi,  const unsigned short* __restrict__ w2t_lo,
    float* __restrict__ aug_t)
{
    __shared__ __align__(16) float xs[68*16];              // 4.35KB
    __shared__ __align__(16) float b1s[64];
    __shared__ __align__(16) float b2s[128];
    __shared__ __align__(16) unsigned short ximh[32*XAS];  // 4.6KB
    __shared__ __align__(16) unsigned short ximl[32*XAS];
    __shared__ __align__(16) unsigned short a1h[32*XAS];
    __shared__ __align__(16) unsigned short a1l[32*XAS];
    __shared__ __align__(16) float outs[A*OTS2];           // 20.9KB

    const int tid = threadIdx.x;
    const int n = blockIdx.y;
    const int b = n >> 3, h = n & 7;
    const int tb0 = blockIdx.x * 64;

    const int lane = tid & 63;
    const int wv   = tid >> 6;
    const int frow = lane & 15;
    const int quad = lane >> 4;

    if (tid < 64)  b1s[tid] = b1[tid];
    if (tid < 128) b2s[tid] = b2[tid];
    {
        const float4* q4 = (const float4*)q + ((long)(b*Lq)*Hq + h)*4;
        float4* xs4 = (float4*)xs;
        for (int i = tid; i < 68*4; i += 256) {
            int rr = i >> 2, e4 = i & 3;
            int t = tb0 + rr; if (t > 255) t = 255;
            xs4[rr*4 + e4] = q4[t*32 + e4];
        }
    }
    __syncthreads();

    const float inv253 = 1.0f / 253.0f;

    #pragma unroll 1
    for (int sub = 0; sub < 2; ++sub) {
        const int t0 = tb0 + sub*32;
        const int l0 = sub*32;

        // ---- pack x-im2col -> bf16 hi/lo. xim[t][k], k=dt*16+i: 48
        // contiguous floats at &xs[(l0+t)*16]. 1 task per thread.
        {
            const int tl = tid >> 3, g = tid & 7;
            if (g < 6) {
                const float* src = &xs[(l0 + tl)*16 + g*8];
                float4 v0 = *(const float4*)src;
                float4 v1 = *(const float4*)(src + 4);
                unsigned short hh[8], ll[8];
                #pragma unroll
                for (int e = 0; e < 4; ++e) {
                    float va = (&v0.x)[e], vb = (&v1.x)[e];
                    unsigned short ha = f2bf(va), hb2 = f2bf(vb);
                    hh[e] = ha;     ll[e] = f2bf(va - bf2f(ha));
                    hh[4+e] = hb2;  ll[4+e] = f2bf(vb - bf2f(hb2));
                }
                *(ushort8*)&ximh[tl*XAS + g*8] = *(ushort8*)hh;
                *(ushort8*)&ximl[tl*XAS + g*8] = *(ushort8*)ll;
            } else {
                const ushort8 z8 = {0,0,0,0,0,0,0,0};
                *(ushort8*)&ximh[tl*XAS + g*8] = z8;
                *(ushort8*)&ximl[tl*XAS + g*8] = z8;
            }
        }
        __syncthreads();

        // ---- conv1 MFMA: wave wv -> c0 = wv*16. 2 mt x 2 ks x 3 products.
        {
            short8 ah[2][2], al[2][2];
            #pragma unroll
            for (int mt = 0; mt < 2; ++mt)
                #pragma unroll
                for (int ks = 0; ks < 2; ++ks) {
                    int ar = (mt*16 + frow)*XAS + ks*32 + quad*8;
                    ah[mt][ks] = *(const short8*)&ximh[ar];
                    al[mt][ks] = *(const short8*)&ximl[ar];
                }
            short8 bh[2], bl[2];
            #pragma unroll
            for (int ks = 0; ks < 2; ++ks) {
                int br = (wv*16 + frow)*64 + ks*32 + quad*8;
                bh[ks] = *(const short8*)(w1im_hi + br);
                bl[ks] = *(const short8*)(w1im_lo + br);
            }
            floatx4 acc1[2];
            acc1[0] = (floatx4){0.f,0.f,0.f,0.f};
            acc1[1] = (floatx4){0.f,0.f,0.f,0.f};
            #pragma unroll
            for (int mt = 0; mt < 2; ++mt)
                #pragma unroll
                for (int ks = 0; ks < 2; ++ks) {
                    acc1[mt] = __builtin_amdgcn_mfma_f32_16x16x32_bf16(ah[mt][ks], bh[ks], acc1[mt], 0,0,0);
                    acc1[mt] = __builtin_amdgcn_mfma_f32_16x16x32_bf16(ah[mt][ks], bl[ks], acc1[mt], 0,0,0);
                    acc1[mt] = __builtin_amdgcn_mfma_f32_16x16x32_bf16(al[mt][ks], bh[ks], acc1[mt], 0,0,0);
                }
            // epilogue: a1[t][c] = acc + b1, split to bf16 hi/lo
            const int c = wv*16 + frow;
            const float bias = b1s[c];
            #pragma unroll
            for (int mt = 0; mt < 2; ++mt)
                #pragma unroll
                for (int e = 0; e < 4; ++e) {
                    int t = mt*16 + quad*4 + e;
                    float v = acc1[mt][e] + bias;
                    unsigned short hb = f2bf(v);
                    a1h[t*XAS + c] = hb;
                    a1l[t*XAS + c] = f2bf(v - bf2f(hb));
                }
        }
        __syncthreads();

        // ---- conv2 MFMA: wave wv -> c0 = wv*32, 2 nt. 2mt x 2nt x 2ks x 3.
        {
            short8 ah[2][2], al[2][2];
            #pragma unroll
            for (int mt = 0; mt < 2; ++mt)
                #pragma unroll
                for (int ks = 0; ks < 2; ++ks) {
                    int ar = (mt*16 + frow)*XAS + ks*32 + quad*8;
                    ah[mt][ks] = *(const short8*)&a1h[ar];
                    al[mt][ks] = *(const short8*)&a1l[ar];
                }
            short8 bh[2][2], bl[2][2];
            #pragma unroll
            for (int nt = 0; nt < 2; ++nt)
                #pragma unroll
                for (int ks = 0; ks < 2; ++ks) {
                    int br = (wv*32 + nt*16 + frow)*64 + ks*32 + quad*8;
                    bh[nt][ks] = *(const short8*)(w2t_hi + br);
                    bl[nt][ks] = *(const short8*)(w2t_lo + br);
                }
            floatx4 acc2[2][2];
            #pragma unroll
            for (int mt = 0; mt < 2; ++mt)
                #pragma unroll
                for (int nt = 0; nt < 2; ++nt)
                    acc2[mt][nt] = (floatx4){0.f,0.f,0.f,0.f};
            #pragma unroll
            for (int mt = 0; mt < 2; ++mt)
                #pragma unroll
                for (int nt = 0; nt < 2; ++nt)
                    #pragma unroll
                    for (int ks = 0; ks < 2; ++ks) {
                        acc2[mt][nt] = __builtin_amdgcn_mfma_f32_16x16x32_bf16(ah[mt][ks], bh[nt][ks], acc2[mt][nt], 0,0,0);
                        acc2[mt][nt] = __builtin_amdgcn_mfma_f32_16x16x32_bf16(ah[mt][ks], bl[nt][ks], acc2[mt][nt], 0,0,0);
                        acc2[mt][nt] = __builtin_amdgcn_mfma_f32_16x16x32_bf16(al[mt][ks], bh[nt][ks], acc2[mt][nt], 0,0,0);
                    }
            // epilogue: bias + ReLU -> outs[(17+c)][t], f4 write (t contig)
            #pragma unroll
            for (int mt = 0; mt < 2; ++mt)
                #pragma unroll
                for (int nt = 0; nt < 2; ++nt) {
                    int c = wv*32 + nt*16 + frow;
                    float bias = b2s[c];
                    float4 vv;
                    vv.x = fmaxf(acc2[mt][nt][0] + bias, 0.f);
                    vv.y = fmaxf(acc2[mt][nt][1] + bias, 0.f);
                    vv.z = fmaxf(acc2[mt][nt][2] + bias, 0.f);
                    vv.w = fmaxf(acc2[mt][nt][3] + bias, 0.f);
                    *(float4*)&outs[(17 + c)*OTS2 + mt*16 + quad*4] = vv;
                }
        }

        // ---- channels 0..16 (trunc x + time) -> outs
        for (int idx = tid; idx < 17*32; idx += 256) {
            int ch = idx >> 5, tt = idx & 31;
            int t = t0 + tt;
            float val = (ch < 16) ? xs[(l0 + tt + 2)*16 + ch] : (float)t * inv253;
            outs[ch*OTS2 + tt] = val;
        }
        __syncthreads();

        // ---- coalesced flush (t>=T garbage masked downstream)
        {
            const long nb = (long)n*A;
            for (int idx = tid; idx < A*32; idx += 256) {
                int row = idx >> 5, tt = idx & 31;
                aug_t[(nb + row)*TPAD + t0 + tt] = outs[row*OTS2 + tt];
            }
        }
        __syncthreads();
    }
}

// ---------------------------------------------------------------------------
// Kernel B: depth-2 signature via MFMA bf16-split GEMM. (R12-proven form.)
// ---------------------------------------------------------------------------
#define CHT 160
#define LDA2 40

__global__ __launch_bounds__(256) void sig_kernel(
    const float* __restrict__ aug_t,
    unsigned short* __restrict__ sig_hi, unsigned short* __restrict__ sig_lo)
{
    __shared__ __align__(16) unsigned short MhT[CHT*LDA2];
    __shared__ __align__(16) unsigned short MlT[CHT*LDA2];
    __shared__ __align__(16) unsigned short DhT[CHT*LDA2];
    __shared__ __align__(16) unsigned short DlT[CHT*LDA2];

    const int tid = threadIdx.x;
    const int n = blockIdx.x;
    const float* an = aug_t + (long)n*A*TPAD;

    const int lane = tid & 63;
    const int w    = tid >> 6;
    const int wm   = w & 1;
    const int wn   = w >> 1;
    const int frow = lane & 15;
    const int quad = lane >> 4;

    const int ch = tid;
    float a0 = 0.f;
    if (ch < A) a0 = an[(long)ch*TPAD];

    floatx4 acc[5][5];
    #pragma unroll
    for (int i = 0; i < 5; ++i)
        #pragma unroll
        for (int j = 0; j < 5; ++j)
            acc[i][j] = (floatx4){0.f, 0.f, 0.f, 0.f};

    for (int c = 0; c < 8; ++c) {
        const int t0 = c*32;
        if (ch < CHT) {
            unsigned short mh[32], ml[32], dh[32], dl[32];
            if (ch < A) {
                float v[33];
                const float* src = an + (long)ch*TPAD + t0;
                #pragma unroll
                for (int i = 0; i < 8; ++i)
                    *(float4*)&v[i*4] = *(const float4*)(src + i*4);
                v[32] = (t0 + 32 <= 253) ? src[32] : 0.f;
                #pragma unroll
                for (int tl = 0; tl < 32; ++tl) {
                    bool valid = (t0 + tl) <= 252;
                    float x0 = v[tl], x1 = v[tl+1];
                    float d = valid ? (x1 - x0) : 0.f;
                    float m = valid ? (0.5f*(x0 + x1) - a0) : 0.f;
                    unsigned short hb = f2bf(m);
                    mh[tl] = hb; ml[tl] = f2bf(m - bf2f(hb));
                    unsigned short db2 = f2bf(d);
                    dh[tl] = db2; dl[tl] = f2bf(d - bf2f(db2));
                }
            } else {
                #pragma unroll
                for (int tl = 0; tl < 32; ++tl) { mh[tl]=0; ml[tl]=0; dh[tl]=0; dl[tl]=0; }
            }
            #pragma unroll
            for (int p = 0; p < 4; ++p) {
                *(ushort8*)&MhT[ch*LDA2 + p*8] = *(ushort8*)&mh[p*8];
                *(ushort8*)&MlT[ch*LDA2 + p*8] = *(ushort8*)&ml[p*8];
                *(ushort8*)&DhT[ch*LDA2 + p*8] = *(ushort8*)&dh[p*8];
                *(ushort8*)&DlT[ch*LDA2 + p*8] = *(ushort8*)&dl[p*8];
            }
        }
        __syncthreads();

        short8 afh[5], afl[5], bfh[5], bfl[5];
        #pragma unroll
        for (int i = 0; i < 5; ++i) {
            int ar = (wm*80 + i*16 + frow)*LDA2 + quad*8;
            int br = (wn*80 + i*16 + frow)*LDA2 + quad*8;
            afh[i] = *(const short8*)&MhT[ar];
            afl[i] = *(const short8*)&MlT[ar];
            bfh[i] = *(const short8*)&DhT[br];
            bfl[i] = *(const short8*)&DlT[br];
        }
        #pragma unroll
        for (int mt = 0; mt < 5; ++mt)
            #pragma unroll
            for (int nt = 0; nt < 5; ++nt) {
                acc[mt][nt] = __builtin_amdgcn_mfma_f32_16x16x32_bf16(
                    afh[mt], bfh[nt], acc[mt][nt], 0, 0, 0);
                acc[mt][nt] = __builtin_amdgcn_mfma_f32_16x16x32_bf16(
                    afh[mt], bfl[nt], acc[mt][nt], 0, 0, 0);
                acc[mt][nt] = __builtin_amdgcn_mfma_f32_16x16x32_bf16(
                    afl[mt], bfh[nt], acc[mt][nt], 0, 0, 0);
            }
        __syncthreads();
    }

    unsigned short* sh = sig_hi + (long)n*KP;
    unsigned short* sl = sig_lo + (long)n*KP;
    if (tid < A) {
        float v = an[(long)tid*TPAD + 253] - a0;
        unsigned short hb = f2bf(v);
        sh[tid] = hb;
        sl[tid] = f2bf(v - bf2f(hb));
    }
    if (tid >= 160 && tid < 160 + (KP - SIG_CH)) {
        sh[SIG_CH + tid - 160] = 0;
        sl[SIG_CH + tid - 160] = 0;
    }
    #pragma unroll
    for (int mt = 0; mt < 5; ++mt)
        #pragma unroll
        for (int nt = 0; nt < 5; ++nt) {
            int j = wn*80 + nt*16 + frow;
            int ib = wm*80 + mt*16 + quad*4;
            #pragma unroll
            for (int e = 0; e < 4; ++e) {
                int i = ib + e;
                if (i < A && j < A) {
                    float v = acc[mt][nt][e];
                    unsigned short hb = f2bf(v);
                    sh[A + i*A + j] = hb;
                    sl[A + i*A + j] = f2bf(v - bf2f(hb));
                }
            }
        }
}

// ---------------------------------------------------------------------------
// Kernel W: W[k][o] fp32 -> Wt_hi/Wt_lo[o][KP] bf16 (transposed, split).
// ---------------------------------------------------------------------------
__global__ __launch_bounds__(256) void wconv_kernel(
    const float* __restrict__ W,
    unsigned short* __restrict__ wt_hi, unsigned short* __restrict__ wt_lo)
{
    __shared__ float ls[64][65];
    const int tid = threadIdx.x;
    const int k0 = blockIdx.x * 64;
    const int o0 = blockIdx.y * 64;

    #pragma unroll
    for (int p = 0; p < 16; ++p) {
        int idx = tid + p*256;
        int kk = idx >> 6, oo = idx & 63;
        int k = k0 + kk;
        ls[kk][oo] = (k < SIG_CH) ? W[(long)k*OUT + o0 + oo] : 0.f;
    }
    __syncthreads();

    const int oo = tid >> 2;
    const int kq = (tid & 3) * 16;
    unsigned short hbuf[16], lbuf[16];
    #pragma unroll
    for (int j = 0; j < 16; ++j) {
        float v = ls[kq + j][oo];
        unsigned short hb = f2bf(v);
        hbuf[j] = hb;
        lbuf[j] = f2bf(v - bf2f(hb));
    }
    long off = (long)(o0 + oo)*KP + k0 + kq;
    *(ushort8*)(wt_hi + off)     = *(ushort8*)&hbuf[0];
    *(ushort8*)(wt_hi + off + 8) = *(ushort8*)&hbuf[8];
    *(ushort8*)(wt_lo + off)     = *(ushort8*)&lbuf[0];
    *(ushort8*)(wt_lo + off + 8) = *(ushort8*)&lbuf[8];
}

// ---------------------------------------------------------------------------
// Kernel C: MFMA bf16 split GEMM. part[z] = sig * Wt^T over K-chunk.
// ---------------------------------------------------------------------------
#define SPLITK 61
#define KC 352
#define NSTEP (KC/32)   // 11
#define LDA 40

__global__ __launch_bounds__(256) void gemm_kernel(
    const unsigned short* __restrict__ sig_hi, const unsigned short* __restrict__ sig_lo,
    const unsigned short* __restrict__ wt_hi,  const unsigned short* __restrict__ wt_lo,
    float* __restrict__ part)
{
    __shared__ __align__(16) unsigned short Ah[128*LDA];
    __shared__ __align__(16) unsigned short Al[128*LDA];
    __shared__ __align__(16) unsigned short Bh[128*LDA];
    __shared__ __align__(16) unsigned short Bl[128*LDA];

    const int tid = threadIdx.x;
    const int o0 = blockIdx.x * 128;
    const int n0 = blockIdx.y * 128;
    const int z  = blockIdx.z;
    const int k0 = z * KC;

    const int lane = tid & 63;
    const int w    = tid >> 6;
    const int wm   = w & 1;
    const int wn   = w >> 1;
    const int frow = lane & 15;
    const int quad = lane >> 4;

    const int srow = tid >> 1;
    const int kh   = (tid & 1) * 16;

    const unsigned short* gAh = sig_hi + (long)(n0 + srow)*KP;
    const unsigned short* gAl = sig_lo + (long)(n0 + srow)*KP;
    const unsigned short* gBh = wt_hi  + (long)(o0 + srow)*KP;
    const unsigned short* gBl = wt_lo  + (long)(o0 + srow)*KP;

    ushort8 rah[2], ral[2], rbh[2], rbl[2];
    const ushort8 z8 = {0,0,0,0,0,0,0,0};

    #define GLOAD(s)                                                          \
        {                                                                     \
            int kb = k0 + (s)*32 + kh;                                        \
            if (kb < KP) {                                                    \
                rah[0] = *(const ushort8*)(gAh + kb);                         \
                rah[1] = *(const ushort8*)(gAh + kb + 8);                     \
                ral[0] = *(const ushort8*)(gAl + kb);                         \
                ral[1] = *(const ushort8*)(gAl + kb + 8);                     \
                rbh[0] = *(const ushort8*)(gBh + kb);                         \
                rbh[1] = *(const ushort8*)(gBh + kb + 8);                     \
                rbl[0] = *(const ushort8*)(gBl + kb);                         \
                rbl[1] = *(const ushort8*)(gBl + kb + 8);                     \
            } else {                                                          \
                rah[0]=z8; rah[1]=z8; ral[0]=z8; ral[1]=z8;                   \
                rbh[0]=z8; rbh[1]=z8; rbl[0]=z8; rbl[1]=z8;                   \
            }                                                                 \
        }

    #define LSTORE()                                                          \
        {                                                                     \
            int o = srow*LDA + kh;                                            \
            *(ushort8*)(Ah + o)     = rah[0];                                 \
            *(ushort8*)(Ah + o + 8) = rah[1];                                 \
            *(ushort8*)(Al + o)     = ral[0];                                 \
            *(ushort8*)(Al + o + 8) = ral[1];                                 \
            *(ushort8*)(Bh + o)     = rbh[0];                                 \
            *(ushort8*)(Bh + o + 8) = rbh[1];                                 \
            *(ushort8*)(Bl + o)     = rbl[0];                                 \
            *(ushort8*)(Bl + o + 8) = rbl[1];                                 \
        }

    floatx4 acc[4][4];
    #pragma unroll
    for (int i = 0; i < 4; ++i)
        #pragma unroll
        for (int j = 0; j < 4; ++j)
            acc[i][j] = (floatx4){0.f, 0.f, 0.f, 0.f};

    GLOAD(0);
    LSTORE();
    __syncthreads();

    for (int s = 0; s < NSTEP; ++s) {
        if (s < NSTEP-1) GLOAD(s+1);

        short8 afh[4], afl[4], bfh[4], bfl[4];
        const int aoff = (wm*64 + frow)*LDA + quad*8;
        const int boff = (wn*64 + frow)*LDA + quad*8;
        #pragma unroll
        for (int tI = 0; tI < 4; ++tI) {
            afh[tI] = *(const short8*)(Ah + aoff + tI*16*LDA);
            afl[tI] = *(const short8*)(Al + aoff + tI*16*LDA);
            bfh[tI] = *(const short8*)(Bh + boff + tI*16*LDA);
            bfl[tI] = *(const short8*)(Bl + boff + tI*16*LDA);
        }
        #pragma unroll
        for (int mt = 0; mt < 4; ++mt)
            #pragma unroll
            for (int nt = 0; nt < 4; ++nt) {
                acc[mt][nt] = __builtin_amdgcn_mfma_f32_16x16x32_bf16(
                    afh[mt], bfh[nt], acc[mt][nt], 0, 0, 0);
                acc[mt][nt] = __builtin_amdgcn_mfma_f32_16x16x32_bf16(
                    afh[mt], bfl[nt], acc[mt][nt], 0, 0, 0);
                acc[mt][nt] = __builtin_amdgcn_mfma_f32_16x16x32_bf16(
                    afl[mt], bfh[nt], acc[mt][nt], 0, 0, 0);
            }
        __syncthreads();
        if (s < NSTEP-1) {
            LSTORE();
            __syncthreads();
        }
    }

    float* pz = part + (long)z * (Nn*OUT);
    #pragma unroll
    for (int mt = 0; mt < 4; ++mt)
        #pragma unroll
        for (int nt = 0; nt < 4; ++nt) {
            int col = o0 + wn*64 + nt*16 + frow;
            int rbase = n0 + wm*64 + mt*16 + quad*4;
            #pragma unroll
            for (int e = 0; e < 4; ++e)
                pz[(long)(rbase + e)*OUT + col] = acc[mt][nt][e];
        }
}

// ---------------------------------------------------------------------------
// Kernel D: out[n][o] = lin_b[o] + sum_z part[z][n][o]
// ---------------------------------------------------------------------------
__global__ __launch_bounds__(256) void reduce_kernel(
    const float* __restrict__ part, const float* __restrict__ lb,
    float* __restrict__ out)
{
    int idx = blockIdx.x * 256 + threadIdx.x;
    float s = lb[idx & 255];
    #pragma unroll 8
    for (int z = 0; z < SPLITK; ++z)
        s += part[(long)z * (Nn*OUT) + idx];
    out[idx] = s;
}

// ---------------------------------------------------------------------------
extern "C" void kernel_launch(void* const* d_in, const int* in_sizes, int n_in,
                              void* d_out, int out_size, void* d_ws, size_t ws_size,
                              hipStream_t stream) {
    const float* q  = (const float*)d_in[0];
    const float* w1 = (const float*)d_in[4];
    const float* b1 = (const float*)d_in[5];
    const float* w2 = (const float*)d_in[6];
    const float* b2 = (const float*)d_in[7];
    const float* lw = (const float*)d_in[8];
    const float* lb = (const float*)d_in[9];
    float* out = (float*)d_out;

    // ws layout — PROVEN 59.4 MB envelope (R12):
    //   [0]          sig_hi  (10,846,208)   [first 48KB doubles as w1im/w2t
    //                                        during wsplit+aug, dead by sig]
    //   [10846208]   sig_lo  (10,846,208)
    //   [21692416]   aug_t fp32 (38,010,880)
    //     aug_t dead after sig_kernel; region reused (stream-ordered):
    //     [21692416] wt_hi (10,846,208)
    //     [32538624] wt_lo (10,846,208)
    //     [43384832] part  (15,990,784)   ends 59,375,616
    char* ws = (char*)d_ws;
    unsigned short* w1im_hi = (unsigned short*)ws;             // 8KB
    unsigned short* w1im_lo = (unsigned short*)(ws + 8192);    // 8KB
    unsigned short* w2t_hi  = (unsigned short*)(ws + 16384);   // 16KB
    unsigned short* w2t_lo  = (unsigned short*)(ws + 32768);   // 16KB (ends 49152)
    unsigned short* sig_hi  = (unsigned short*)ws;
    unsigned short* sig_lo  = (unsigned short*)(ws + 10846208);
    float*          aug_t   = (float*)(ws + 21692416);
    unsigned short* wt_hi   = (unsigned short*)(ws + 21692416);
    unsigned short* wt_lo   = (unsigned short*)(ws + 32538624);
    float*          part    = (float*)(ws + 43384832);

    wsplit_kernel<<<48, 256, 0, stream>>>(w1, w2, w1im_hi, w1im_lo, w2t_hi, w2t_lo);
    aug_kernel<<<dim3(4, Nn), 256, 0, stream>>>(q, b1, b2, w1im_hi, w1im_lo, w2t_hi, w2t_lo, aug_t);
    sig_kernel<<<Nn, 256, 0, stream>>>(aug_t, sig_hi, sig_lo);
    wconv_kernel<<<dim3(KP/64, OUT/64), 256, 0, stream>>>(lw, wt_hi, wt_lo);
    gemm_kernel<<<dim3(2, 2, SPLITK), 256, 0, stream>>>(sig_hi, sig_lo, wt_hi, wt_lo, part);
    reduce_kernel<<<(Nn*OUT)/256, 256, 0, stream>>>(part, lb, out);
}

// Round 14
// 170.891 us; speedup vs baseline: 1.2874x; 1.0596x over previous
//
#include <hip/hip_runtime.h>
#include <hip/hip_bf16.h>

// Problem constants
#define Bq 32
#define Lq 256
#define Hq 8
#define Eq 16
#define Nn (Bq*Hq)        // 256 sequences
#define T 254             // Lq - 3 + 1
#define A 145             // E + 1 + 128 augmented channels
#define SIG_CH (A + A*A)  // 21170
#define KP 21184          // padded K (mult of 32), bf16 arrays
#define OUT 256

typedef __attribute__((ext_vector_type(8))) short short8;
typedef __attribute__((ext_vector_type(8))) unsigned short ushort8;
typedef __attribute__((ext_vector_type(4))) float floatx4;

static __device__ __forceinline__ unsigned short f2bf(float v) {
    unsigned int u = __float_as_uint(v);
    unsigned int r = (u + 0x7FFFu + ((u >> 16) & 1u)) >> 16;
    return (unsigned short)r;
}
static __device__ __forceinline__ float bf2f(unsigned short b) {
    return __uint_as_float(((unsigned int)b) << 16);
}

// ---------------------------------------------------------------------------
// Kernel P: weight prep. w1[48][64] -> w1im[c=64][k=64 pad0] bf16 hi/lo;
// w2[64][128] -> w2t[c=128][i=64] bf16 hi/lo. grid(48) x 256.
// ---------------------------------------------------------------------------
__global__ __launch_bounds__(256) void wsplit_kernel(
    const float* __restrict__ w1, const float* __restrict__ w2,
    unsigned short* __restrict__ w1im_hi, unsigned short* __restrict__ w1im_lo,
    unsigned short* __restrict__ w2t_hi,  unsigned short* __restrict__ w2t_lo)
{
    int idx = blockIdx.x*256 + threadIdx.x;   // 0..12287
    if (idx < 4096) {
        int c = idx & 63, k = idx >> 6;
        float v = (k < 48) ? w1[k*64 + c] : 0.f;
        unsigned short hb = f2bf(v);
        w1im_hi[c*64 + k] = hb;
        w1im_lo[c*64 + k] = f2bf(v - bf2f(hb));
    } else {
        int j = idx - 4096;
        int c = j & 127, i = j >> 7;
        float v = w2[i*128 + c];
        unsigned short hb = f2bf(v);
        w2t_hi[c*64 + i] = hb;
        w2t_lo[c*64 + i] = f2bf(v - bf2f(hb));
    }
}

// ---------------------------------------------------------------------------
// Kernel AS: FUSED aug+sig. One block per n, 256 thr = 4 waves.
// Per 32-t chunk: stage x -> im2col pack (48 rows, 33 valid) -> conv1 MFMA
// -> conv2 MFMA + ReLU -> outs[145][36] -> M/D pack (M split hi/lo, D hi
// only) -> signature MFMA (5x5 tiles/wave, 2 products). aug never hits HBM.
// LDS 62.4KB static; xim/a1 alias the M/D region (liveness-disjoint).
// ---------------------------------------------------------------------------
#define MDS 40    // M/D row stride (ushorts)
#define OS3 36    // outs row stride (floats)
#define XIS 72    // xim/a1 row stride (ushorts)

__global__ __launch_bounds__(256) void augsig_kernel(
    const float* __restrict__ q,
    const float* __restrict__ b1, const float* __restrict__ b2,
    const unsigned short* __restrict__ w1im_hi, const unsigned short* __restrict__ w1im_lo,
    const unsigned short* __restrict__ w2t_hi,  const unsigned short* __restrict__ w2t_lo,
    unsigned short* __restrict__ sig_hi, unsigned short* __restrict__ sig_lo)
{
    __shared__ __align__(16) unsigned short mdb[3*160*MDS]; // 38.4KB
    __shared__ __align__(16) float outs[A*OS3];             // 20.9KB
    __shared__ __align__(16) float xsc[36*16];              // 2.3KB (35 rows used)
    __shared__ __align__(16) float b1s[64];
    __shared__ __align__(16) float b2s[128];

    unsigned short* Mh = mdb;                 // 160*40
    unsigned short* Ml = mdb + 160*MDS;
    unsigned short* Dh = mdb + 2*160*MDS;
    // aliases (dead when M/D live; rewritten by MDpack every chunk):
    unsigned short* ximh = mdb;               // 48*72 = 3456
    unsigned short* ximl = mdb + 3456;
    unsigned short* a1h  = mdb + 6912;
    unsigned short* a1l  = mdb + 10368;       // ends 13824

    const int tid = threadIdx.x;
    const int n = blockIdx.x;
    const int b = n >> 3, h = n & 7;

    const int lane = tid & 63;
    const int wv   = tid >> 6;
    const int frow = lane & 15;
    const int quad = lane >> 4;
    const int wm = wv & 1, wn = wv >> 1;

    if (tid < 64)  b1s[tid] = b1[tid];
    if (tid < 128) b2s[tid] = b2[tid];

    const float4* q4 = (const float4*)q + ((long)(b*Lq)*Hq + h)*4;
    const float inv253 = 1.0f / 253.0f;

    float a0 = 0.f, vlast = 0.f;

    floatx4 acc[5][5];
    #pragma unroll
    for (int i = 0; i < 5; ++i)
        #pragma unroll
        for (int j = 0; j < 5; ++j)
            acc[i][j] = (floatx4){0.f, 0.f, 0.f, 0.f};

    #pragma unroll 1
    for (int c = 0; c < 8; ++c) {
        const int t0 = c*32;

        // ---- stage x rows t0..t0+34 (clamped)
        if (tid < 140) {
            int r = tid >> 2, e4 = tid & 3;
            int t = t0 + r; if (t > 255) t = 255;
            *((float4*)xsc + (r*4 + e4)) = q4[t*32 + e4];
        }
        __syncthreads();   // B1: xsc ready; mdb free (prev MFMA done)

        // ---- im2col pack: xim[t][k], 48 rows (t<=32 real, rest 0)
        for (int idx = tid; idx < 48*8; idx += 256) {
            int r = idx >> 3, g = idx & 7;
            unsigned short hh[8], ll[8];
            if (r <= 32 && g < 6) {
                const float* src = &xsc[r*16 + g*8];   // 48 contig floats/row
                #pragma unroll
                for (int e = 0; e < 8; ++e) {
                    float v = src[e];
                    unsigned short hb = f2bf(v);
                    hh[e] = hb; ll[e] = f2bf(v - bf2f(hb));
                }
            } else {
                #pragma unroll
                for (int e = 0; e < 8; ++e) { hh[e] = 0; ll[e] = 0; }
            }
            *(ushort8*)&ximh[r*XIS + g*8] = *(ushort8*)hh;
            *(ushort8*)&ximl[r*XIS + g*8] = *(ushort8*)ll;
        }
        __syncthreads();   // B2

        // ---- conv1 MFMA: 48t x 64c, K=64. wave -> c0 = wv*16.
        {
            short8 ah[3][2], al[3][2];
            #pragma unroll
            for (int mt = 0; mt < 3; ++mt)
                #pragma unroll
                for (int ks = 0; ks < 2; ++ks) {
                    int ar = (mt*16 + frow)*XIS + ks*32 + quad*8;
                    ah[mt][ks] = *(const short8*)&ximh[ar];
                    al[mt][ks] = *(const short8*)&ximl[ar];
                }
            short8 bh[2], bl[2];
            #pragma unroll
            for (int ks = 0; ks < 2; ++ks) {
                int br = (wv*16 + frow)*64 + ks*32 + quad*8;
                bh[ks] = *(const short8*)(w1im_hi + br);
                bl[ks] = *(const short8*)(w1im_lo + br);
            }
            floatx4 acc1[3];
            #pragma unroll
            for (int mt = 0; mt < 3; ++mt) acc1[mt] = (floatx4){0.f,0.f,0.f,0.f};
            #pragma unroll
            for (int mt = 0; mt < 3; ++mt)
                #pragma unroll
                for (int ks = 0; ks < 2; ++ks) {
                    acc1[mt] = __builtin_amdgcn_mfma_f32_16x16x32_bf16(ah[mt][ks], bh[ks], acc1[mt], 0,0,0);
                    acc1[mt] = __builtin_amdgcn_mfma_f32_16x16x32_bf16(ah[mt][ks], bl[ks], acc1[mt], 0,0,0);
                    acc1[mt] = __builtin_amdgcn_mfma_f32_16x16x32_bf16(al[mt][ks], bh[ks], acc1[mt], 0,0,0);
                }
            const int cc = wv*16 + frow;
            const float bias = b1s[cc];
            #pragma unroll
            for (int mt = 0; mt < 3; ++mt)
                #pragma unroll
                for (int e = 0; e < 4; ++e) {
                    int t = mt*16 + quad*4 + e;
                    float v = acc1[mt][e] + bias;
                    unsigned short hb = f2bf(v);
                    a1h[t*XIS + cc] = hb;
                    a1l[t*XIS + cc] = f2bf(v - bf2f(hb));
                }
        }
        __syncthreads();   // B3

        // ---- conv2 MFMA: 48t x 128c, K=64. wave -> c0 = wv*32, 2 nt.
        {
            short8 ah[3][2], al[3][2];
            #pragma unroll
            for (int mt = 0; mt < 3; ++mt)
                #pragma unroll
                for (int ks = 0; ks < 2; ++ks) {
                    int ar = (mt*16 + frow)*XIS + ks*32 + quad*8;
                    ah[mt][ks] = *(const short8*)&a1h[ar];
                    al[mt][ks] = *(const short8*)&a1l[ar];
                }
            short8 bh[2][2], bl[2][2];
            #pragma unroll
            for (int nt = 0; nt < 2; ++nt)
                #pragma unroll
                for (int ks = 0; ks < 2; ++ks) {
                    int br = (wv*32 + nt*16 + frow)*64 + ks*32 + quad*8;
                    bh[nt][ks] = *(const short8*)(w2t_hi + br);
                    bl[nt][ks] = *(const short8*)(w2t_lo + br);
                }
            floatx4 acc2[3][2];
            #pragma unroll
            for (int mt = 0; mt < 3; ++mt)
                #pragma unroll
                for (int nt = 0; nt < 2; ++nt)
                    acc2[mt][nt] = (floatx4){0.f,0.f,0.f,0.f};
            #pragma unroll
            for (int mt = 0; mt < 3; ++mt)
                #pragma unroll
                for (int nt = 0; nt < 2; ++nt)
                    #pragma unroll
                    for (int ks = 0; ks < 2; ++ks) {
                        acc2[mt][nt] = __builtin_amdgcn_mfma_f32_16x16x32_bf16(ah[mt][ks], bh[nt][ks], acc2[mt][nt], 0,0,0);
                        acc2[mt][nt] = __builtin_amdgcn_mfma_f32_16x16x32_bf16(ah[mt][ks], bl[nt][ks], acc2[mt][nt], 0,0,0);
                        acc2[mt][nt] = __builtin_amdgcn_mfma_f32_16x16x32_bf16(al[mt][ks], bh[nt][ks], acc2[mt][nt], 0,0,0);
                    }
            #pragma unroll
            for (int mt = 0; mt < 3; ++mt)
                #pragma unroll
                for (int nt = 0; nt < 2; ++nt) {
                    int cc = wv*32 + nt*16 + frow;
                    float bias = b2s[cc];
                    int tb = mt*16 + quad*4;
                    if (tb <= 32) {   // row 36 floats: cols 32..35 in-bounds
                        float4 vv;
                        vv.x = fmaxf(acc2[mt][nt][0] + bias, 0.f);
                        vv.y = fmaxf(acc2[mt][nt][1] + bias, 0.f);
                        vv.z = fmaxf(acc2[mt][nt][2] + bias, 0.f);
                        vv.w = fmaxf(acc2[mt][nt][3] + bias, 0.f);
                        *(float4*)&outs[(17 + cc)*OS3 + tb] = vv;
                    }
                }
        }
        // ---- channels 0..16 (trunc x + time), cols 0..32
        for (int idx = tid; idx < 17*33; idx += 256) {
            int ch = idx / 33, tt = idx - ch*33;
            float val = (ch < 16) ? xsc[(tt+2)*16 + ch] : (float)(t0+tt)*inv253;
            outs[ch*OS3 + tt] = val;
        }
        __syncthreads();   // B4: outs ready

        // ---- M/D pack (M split hi/lo, D hi only); capture a0 / vlast
        if (tid < 160) {
            unsigned short mh[32], ml[32], dh[32];
            if (tid < A) {
                float v[33];
                #pragma unroll
                for (int i = 0; i < 8; ++i)
                    *(float4*)&v[i*4] = *(const float4*)&outs[tid*OS3 + i*4];
                v[32] = outs[tid*OS3 + 32];
                if (c == 0) a0 = v[0];
                if (c == 7) vlast = v[29];   // aug[253]
                #pragma unroll
                for (int tl = 0; tl < 32; ++tl) {
                    bool valid = (t0 + tl) <= 252;
                    float x0 = v[tl], x1 = v[tl+1];
                    float d = valid ? (x1 - x0) : 0.f;
                    float m = valid ? (0.5f*(x0 + x1) - a0) : 0.f;
                    unsigned short hb = f2bf(m);
                    mh[tl] = hb; ml[tl] = f2bf(m - bf2f(hb));
                    dh[tl] = f2bf(d);
                }
            } else {
                #pragma unroll
                for (int tl = 0; tl < 32; ++tl) { mh[tl]=0; ml[tl]=0; dh[tl]=0; }
            }
            #pragma unroll
            for (int pp = 0; pp < 4; ++pp) {
                *(ushort8*)&Mh[tid*MDS + pp*8] = *(ushort8*)&mh[pp*8];
                *(ushort8*)&Ml[tid*MDS + pp*8] = *(ushort8*)&ml[pp*8];
                *(ushort8*)&Dh[tid*MDS + pp*8] = *(ushort8*)&dh[pp*8];
            }
        }
        __syncthreads();   // B5: M/D ready

        // ---- signature MFMA: 5x5 tiles/wave, 2 products (M split, D hi)
        {
            short8 afh[5], afl[5], bfh[5];
            #pragma unroll
            for (int i = 0; i < 5; ++i) {
                int ar = (wm*80 + i*16 + frow)*MDS + quad*8;
                int br = (wn*80 + i*16 + frow)*MDS + quad*8;
                afh[i] = *(const short8*)&Mh[ar];
                afl[i] = *(const short8*)&Ml[ar];
                bfh[i] = *(const short8*)&Dh[br];
            }
            #pragma unroll
            for (int mt = 0; mt < 5; ++mt)
                #pragma unroll
                for (int nt = 0; nt < 5; ++nt) {
                    acc[mt][nt] = __builtin_amdgcn_mfma_f32_16x16x32_bf16(
                        afh[mt], bfh[nt], acc[mt][nt], 0, 0, 0);
                    acc[mt][nt] = __builtin_amdgcn_mfma_f32_16x16x32_bf16(
                        afl[mt], bfh[nt], acc[mt][nt], 0, 0, 0);
                }
        }
        // no barrier: next chunk's xsc stage touches different region; B1 guards mdb
    }

    // ---- epilogue: compensated bf16 split of s1 and s2
    unsigned short* sh = sig_hi + (long)n*KP;
    unsigned short* sl = sig_lo + (long)n*KP;
    if (tid < A) {
        float v = vlast - a0;
        unsigned short hb = f2bf(v);
        sh[tid] = hb;
        sl[tid] = f2bf(v - bf2f(hb));
    }
    if (tid >= 160 && tid < 160 + (KP - SIG_CH)) {
        sh[SIG_CH + tid - 160] = 0;
        sl[SIG_CH + tid - 160] = 0;
    }
    #pragma unroll
    for (int mt = 0; mt < 5; ++mt)
        #pragma unroll
        for (int nt = 0; nt < 5; ++nt) {
            int j = wn*80 + nt*16 + frow;
            int ib = wm*80 + mt*16 + quad*4;
            #pragma unroll
            for (int e = 0; e < 4; ++e) {
                int i = ib + e;
                if (i < A && j < A) {
                    float v = acc[mt][nt][e];
                    unsigned short hb = f2bf(v);
                    sh[A + i*A + j] = hb;
                    sl[A + i*A + j] = f2bf(v - bf2f(hb));
                }
            }
        }
}

// ---------------------------------------------------------------------------
// Kernel W: W[k][o] fp32 -> Wt_hi/Wt_lo[o][KP] bf16 (transposed, split).
// ---------------------------------------------------------------------------
__global__ __launch_bounds__(256) void wconv_kernel(
    const float* __restrict__ W,
    unsigned short* __restrict__ wt_hi, unsigned short* __restrict__ wt_lo)
{
    __shared__ float ls[64][65];
    const int tid = threadIdx.x;
    const int k0 = blockIdx.x * 64;
    const int o0 = blockIdx.y * 64;

    #pragma unroll
    for (int p = 0; p < 16; ++p) {
        int idx = tid + p*256;
        int kk = idx >> 6, oo = idx & 63;
        int k = k0 + kk;
        ls[kk][oo] = (k < SIG_CH) ? W[(long)k*OUT + o0 + oo] : 0.f;
    }
    __syncthreads();

    const int oo = tid >> 2;
    const int kq = (tid & 3) * 16;
    unsigned short hbuf[16], lbuf[16];
    #pragma unroll
    for (int j = 0; j < 16; ++j) {
        float v = ls[kq + j][oo];
        unsigned short hb = f2bf(v);
        hbuf[j] = hb;
        lbuf[j] = f2bf(v - bf2f(hb));
    }
    long off = (long)(o0 + oo)*KP + k0 + kq;
    *(ushort8*)(wt_hi + off)     = *(ushort8*)&hbuf[0];
    *(ushort8*)(wt_hi + off + 8) = *(ushort8*)&hbuf[8];
    *(ushort8*)(wt_lo + off)     = *(ushort8*)&lbuf[0];
    *(ushort8*)(wt_lo + off + 8) = *(ushort8*)&lbuf[8];
}

// ---------------------------------------------------------------------------
// Kernel C: MFMA bf16 split GEMM. part[z] = sig * Wt^T over K-chunk.
// ---------------------------------------------------------------------------
#define SPLITK 61
#define KC 352
#define NSTEP (KC/32)   // 11
#define LDA 40

__global__ __launch_bounds__(256) void gemm_kernel(
    const unsigned short* __restrict__ sig_hi, const unsigned short* __restrict__ sig_lo,
    const unsigned short* __restrict__ wt_hi,  const unsigned short* __restrict__ wt_lo,
    float* __restrict__ part)
{
    __shared__ __align__(16) unsigned short Ah[128*LDA];
    __shared__ __align__(16) unsigned short Al[128*LDA];
    __shared__ __align__(16) unsigned short Bh[128*LDA];
    __shared__ __align__(16) unsigned short Bl[128*LDA];

    const int tid = threadIdx.x;
    const int o0 = blockIdx.x * 128;
    const int n0 = blockIdx.y * 128;
    const int z  = blockIdx.z;
    const int k0 = z * KC;

    const int lane = tid & 63;
    const int w    = tid >> 6;
    const int wm   = w & 1;
    const int wn   = w >> 1;
    const int frow = lane & 15;
    const int quad = lane >> 4;

    const int srow = tid >> 1;
    const int kh   = (tid & 1) * 16;

    const unsigned short* gAh = sig_hi + (long)(n0 + srow)*KP;
    const unsigned short* gAl = sig_lo + (long)(n0 + srow)*KP;
    const unsigned short* gBh = wt_hi  + (long)(o0 + srow)*KP;
    const unsigned short* gBl = wt_lo  + (long)(o0 + srow)*KP;

    ushort8 rah[2], ral[2], rbh[2], rbl[2];
    const ushort8 z8 = {0,0,0,0,0,0,0,0};

    #define GLOAD(s)                                                          \
        {                                                                     \
            int kb = k0 + (s)*32 + kh;                                        \
            if (kb < KP) {                                                    \
                rah[0] = *(const ushort8*)(gAh + kb);                         \
                rah[1] = *(const ushort8*)(gAh + kb + 8);                     \
                ral[0] = *(const ushort8*)(gAl + kb);                         \
                ral[1] = *(const ushort8*)(gAl + kb + 8);                     \
                rbh[0] = *(const ushort8*)(gBh + kb);                         \
                rbh[1] = *(const ushort8*)(gBh + kb + 8);                     \
                rbl[0] = *(const ushort8*)(gBl + kb);                         \
                rbl[1] = *(const ushort8*)(gBl + kb + 8);                     \
            } else {                                                          \
                rah[0]=z8; rah[1]=z8; ral[0]=z8; ral[1]=z8;                   \
                rbh[0]=z8; rbh[1]=z8; rbl[0]=z8; rbl[1]=z8;                   \
            }                                                                 \
        }

    #define LSTORE()                                                          \
        {                                                                     \
            int o = srow*LDA + kh;                                            \
            *(ushort8*)(Ah + o)     = rah[0];                                 \
            *(ushort8*)(Ah + o + 8) = rah[1];                                 \
            *(ushort8*)(Al + o)     = ral[0];                                 \
            *(ushort8*)(Al + o + 8) = ral[1];                                 \
            *(ushort8*)(Bh + o)     = rbh[0];                                 \
            *(ushort8*)(Bh + o + 8) = rbh[1];                                 \
            *(ushort8*)(Bl + o)     = rbl[0];                                 \
            *(ushort8*)(Bl + o + 8) = rbl[1];                                 \
        }

    floatx4 acc[4][4];
    #pragma unroll
    for (int i = 0; i < 4; ++i)
        #pragma unroll
        for (int j = 0; j < 4; ++j)
            acc[i][j] = (floatx4){0.f, 0.f, 0.f, 0.f};

    GLOAD(0);
    LSTORE();
    __syncthreads();

    for (int s = 0; s < NSTEP; ++s) {
        if (s < NSTEP-1) GLOAD(s+1);

        short8 afh[4], afl[4], bfh[4], bfl[4];
        const int aoff = (wm*64 + frow)*LDA + quad*8;
        const int boff = (wn*64 + frow)*LDA + quad*8;
        #pragma unroll
        for (int tI = 0; tI < 4; ++tI) {
            afh[tI] = *(const short8*)(Ah + aoff + tI*16*LDA);
            afl[tI] = *(const short8*)(Al + aoff + tI*16*LDA);
            bfh[tI] = *(const short8*)(Bh + boff + tI*16*LDA);
            bfl[tI] = *(const short8*)(Bl + boff + tI*16*LDA);
        }
        #pragma unroll
        for (int mt = 0; mt < 4; ++mt)
            #pragma unroll
            for (int nt = 0; nt < 4; ++nt) {
                acc[mt][nt] = __builtin_amdgcn_mfma_f32_16x16x32_bf16(
                    afh[mt], bfh[nt], acc[mt][nt], 0, 0, 0);
                acc[mt][nt] = __builtin_amdgcn_mfma_f32_16x16x32_bf16(
                    afh[mt], bfl[nt], acc[mt][nt], 0, 0, 0);
                acc[mt][nt] = __builtin_amdgcn_mfma_f32_16x16x32_bf16(
                    afl[mt], bfh[nt], acc[mt][nt], 0, 0, 0);
            }
        __syncthreads();
        if (s < NSTEP-1) {
            LSTORE();
            __syncthreads();
        }
    }

    float* pz = part + (long)z * (Nn*OUT);
    #pragma unroll
    for (int mt = 0; mt < 4; ++mt)
        #pragma unroll
        for (int nt = 0; nt < 4; ++nt) {
            int col = o0 + wn*64 + nt*16 + frow;
            int rbase = n0 + wm*64 + mt*16 + quad*4;
            #pragma unroll
            for (int e = 0; e < 4; ++e)
                pz[(long)(rbase + e)*OUT + col] = acc[mt][nt][e];
        }
}

// ---------------------------------------------------------------------------
// Kernel D: out[n][o] = lin_b[o] + sum_z part[z][n][o]
// ---------------------------------------------------------------------------
__global__ __launch_bounds__(256) void reduce_kernel(
    const float* __restrict__ part, const float* __restrict__ lb,
    float* __restrict__ out)
{
    int idx = blockIdx.x * 256 + threadIdx.x;
    float s = lb[idx & 255];
    #pragma unroll 8
    for (int z = 0; z < SPLITK; ++z)
        s += part[(long)z * (Nn*OUT) + idx];
    out[idx] = s;
}

// ---------------------------------------------------------------------------
extern "C" void kernel_launch(void* const* d_in, const int* in_sizes, int n_in,
                              void* d_out, int out_size, void* d_ws, size_t ws_size,
                              hipStream_t stream) {
    const float* q  = (const float*)d_in[0];
    const float* w1 = (const float*)d_in[4];
    const float* b1 = (const float*)d_in[5];
    const float* w2 = (const float*)d_in[6];
    const float* b2 = (const float*)d_in[7];
    const float* lw = (const float*)d_in[8];
    const float* lb = (const float*)d_in[9];
    float* out = (float*)d_out;

    // ws layout — 59.4 MB (within proven envelope), aug_t eliminated:
    //   [0]          sig_hi (10,846,208)
    //   [10846208]   sig_lo (10,846,208)
    //   [21692416]   wt_hi  (10,846,208)
    //   [32538624]   wt_lo  (10,846,208)
    //   [43384832]   part   (15,990,784)  ends 59,375,616
    //     w1im/w2t (48KB) live at part base until gemm overwrites (dead then)
    char* ws = (char*)d_ws;
    unsigned short* sig_hi  = (unsigned short*)ws;
    unsigned short* sig_lo  = (unsigned short*)(ws + 10846208);
    unsigned short* wt_hi   = (unsigned short*)(ws + 21692416);
    unsigned short* wt_lo   = (unsigned short*)(ws + 32538624);
    float*          part    = (float*)(ws + 43384832);
    unsigned short* w1im_hi = (unsigned short*)(ws + 43384832);           // 8KB
    unsigned short* w1im_lo = (unsigned short*)(ws + 43384832 + 8192);    // 8KB
    unsigned short* w2t_hi  = (unsigned short*)(ws + 43384832 + 16384);   // 16KB
    unsigned short* w2t_lo  = (unsigned short*)(ws + 43384832 + 32768);   // 16KB

    wsplit_kernel<<<48, 256, 0, stream>>>(w1, w2, w1im_hi, w1im_lo, w2t_hi, w2t_lo);
    augsig_kernel<<<Nn, 256, 0, stream>>>(q, b1, b2, w1im_hi, w1im_lo, w2t_hi, w2t_lo, sig_hi, sig_lo);
    wconv_kernel<<<dim3(KP/64, OUT/64), 256, 0, stream>>>(lw, wt_hi, wt_lo);
    gemm_kernel<<<dim3(2, 2, SPLITK), 256, 0, stream>>>(sig_hi, sig_lo, wt_hi, wt_lo, part);
    reduce_kernel<<<(Nn*OUT)/256, 256, 0, stream>>>(part, lb, out);
}